// Round 7
// baseline (463.275 us; speedup 1.0000x reference)
//
#include <hip/hip_runtime.h>
#include <hip/hip_bf16.h>

typedef __hip_bfloat16 bf16;
typedef __bf16 bf16x8 __attribute__((ext_vector_type(8)));
typedef float f32x4 __attribute__((ext_vector_type(4)));

#define B_  2
#define L_  2048
#define D_  1024
#define DIN 2048
#define NST 16
#define T_  (B_ * L_)   // 4096 tokens
#define NCH 32          // scan chunks per sequence
#define CH  64          // tokens per chunk
#define NEXT 2176       // DIN + 128 fused B/C columns for gemm<1>

// Static fallback scratch if harness d_ws is too small (~158 MiB needed).
#define WS_NEEDED 165000000ull
__device__ __align__(256) char g_scratch[184549376];   // 176 MiB

__device__ __forceinline__ float b2f(bf16 v) { return __bfloat162float(v); }
__device__ __forceinline__ bf16 f2b(float v) { return __float2bfloat16(v); }

__device__ __forceinline__ void async16(const bf16* g, bf16* l) {
    __builtin_amdgcn_global_load_lds((const __attribute__((address_space(1))) unsigned int*)g,
                                     (__attribute__((address_space(3))) unsigned int*)l, 16, 0, 0);
}

// ---------------------------------------------------------------- transpose + fp32->bf16
__global__ __launch_bounds__(256) void transpose_f2b(const float* __restrict__ in,
                                                     bf16* __restrict__ out, int R, int C) {
    __shared__ float t[32][33];
    int c0 = blockIdx.x * 32, r0 = blockIdx.y * 32;
    int tx = threadIdx.x & 31, ty = threadIdx.x >> 5;
    #pragma unroll
    for (int i = 0; i < 32; i += 8)
        t[ty + i][tx] = in[(size_t)(r0 + ty + i) * C + c0 + tx];
    __syncthreads();
    #pragma unroll
    for (int i = 0; i < 32; i += 8)
        out[(size_t)(c0 + ty + i) * R + r0 + tx] = f2b(t[tx][ty + i]);
}

// ---------------------------------------------------------------- w_b/w_c rows of extended weight
// writes rows [2048, 2176) of wT_dbc: 16 rows w_b^T, 16 rows w_c^T, 96 zero rows
__global__ __launch_bounds__(256) void bcw_prep(const float* __restrict__ wb,
                                                const float* __restrict__ wc,
                                                bf16* __restrict__ dst) {
    int k = blockIdx.x * 256 + threadIdx.x;   // 0..2047
    int rn = blockIdx.y;                       // 0..127
    float v = 0.f;
    if (rn < 16) v = wb[(size_t)k * 16 + rn];
    else if (rn < 32) v = wc[(size_t)k * 16 + (rn - 16)];
    dst[(size_t)(2048 + rn) * 2048 + k] = f2b(v);
}

// ---------------------------------------------------------------- layernorm (fp32 in, bf16 out)
__global__ __launch_bounds__(256) void ln_kernel(const float* __restrict__ x,
                                                 const float* __restrict__ w,
                                                 const float* __restrict__ bb,
                                                 bf16* __restrict__ xn) {
    int tok = blockIdx.x, tid = threadIdx.x;
    const float* xr = x + (size_t)tok * D_;
    float4 v4 = ((const float4*)xr)[tid];
    float v[4] = {v4.x, v4.y, v4.z, v4.w};
    float s = 0.f, ss = 0.f;
    #pragma unroll
    for (int i = 0; i < 4; i++) { s += v[i]; ss += v[i] * v[i]; }
    #pragma unroll
    for (int o = 32; o > 0; o >>= 1) { s += __shfl_down(s, o); ss += __shfl_down(ss, o); }
    __shared__ float rs[4], rss[4], mv[2];
    if ((tid & 63) == 0) { rs[tid >> 6] = s; rss[tid >> 6] = ss; }
    __syncthreads();
    if (tid == 0) {
        float S = rs[0] + rs[1] + rs[2] + rs[3];
        float SS = rss[0] + rss[1] + rss[2] + rss[3];
        float mu = S * (1.f / D_);
        float var = SS * (1.f / D_) - mu * mu;
        mv[0] = mu; mv[1] = rsqrtf(fmaxf(var, 0.f) + 1e-5f);
    }
    __syncthreads();
    float mu = mv[0], rstd = mv[1];
    float4 wv = ((const float4*)w)[tid];
    float4 bv = ((const float4*)bb)[tid];
    float wa[4] = {wv.x, wv.y, wv.z, wv.w};
    float ba[4] = {bv.x, bv.y, bv.z, bv.w};
    union { uint2 u; bf16 h[4]; } q;
    #pragma unroll
    for (int i = 0; i < 4; i++)
        q.h[i] = f2b((v[i] - mu) * rstd * wa[i] + ba[i]);
    ((uint2*)(xn + (size_t)tok * D_))[tid] = q.u;
}

// ---------------------------------------------------------------- GEMM 128xNT, async LDS staging
// C[M,N] = A[M,K] @ Bt[N,K]^T
// EPI 0: store bf16 | 1: cols<2048 +bias,softplus->fp32 delta; cols 2048..2079 -> Bq/Cq
//     2: +resid(fp32), store fp32
template <int EPI, int NT>
__global__ __launch_bounds__(256) void gemm128(const bf16* __restrict__ A,
                                               const bf16* __restrict__ Bt,
                                               int K, void* __restrict__ Cout,
                                               const float* __restrict__ extra, int ldc,
                                               float* __restrict__ Bqp, float* __restrict__ Cqp) {
    constexpr int JN = NT / 32;          // B-frags per wave (4 for NT=128, 2 for NT=64)
    __shared__ __align__(16) bf16 As[128 * 32];
    __shared__ __align__(16) bf16 Bs[NT * 32];
    const int tid = threadIdx.x;
    const int lane = tid & 63;
    const int wave = tid >> 6;
    const int bm = blockIdx.y * 128, bn = blockIdx.x * NT;
    const int wm = (wave & 1) * 64, wn = (wave >> 1) * (NT / 2);
    f32x4 acc[4][JN];
    #pragma unroll
    for (int i = 0; i < 4; i++)
        #pragma unroll
        for (int j = 0; j < JN; j++) acc[i][j] = (f32x4){0.f, 0.f, 0.f, 0.f};

    const int r = tid >> 2;   // 0..63
    const int c = tid & 3;    // 16B chunk in 32-elem k-slab
    const bf16* ga  = A  + (size_t)(bm + r) * K + c * 8;
    const bf16* gb  = Bt + (size_t)(bn + r) * K + c * 8;
    const bf16* ga2 = ga + (size_t)64 * K;
    bf16* la  = As + tid * 8;
    bf16* lb  = Bs + tid * 8;
    bf16* la2 = la + 64 * 32;

    const int fm = lane & 15;
    const int fk = (lane >> 4) * 8;

    for (int k0 = 0; k0 < K; k0 += 32) {
        async16(ga + k0, la);
        async16(ga2 + k0, la2);
        async16(gb + k0, lb);
        if constexpr (NT == 128) async16(gb + (size_t)64 * K + k0, lb + 64 * 32);
        __syncthreads();
        bf16x8 af[4], bfr[JN];
        #pragma unroll
        for (int i = 0; i < 4; i++)
            af[i] = *(const bf16x8*)(As + (wm + i * 16 + fm) * 32 + fk);
        #pragma unroll
        for (int j = 0; j < JN; j++)
            bfr[j] = *(const bf16x8*)(Bs + (wn + j * 16 + fm) * 32 + fk);
        #pragma unroll
        for (int i = 0; i < 4; i++)
            #pragma unroll
            for (int j = 0; j < JN; j++)
                acc[i][j] = __builtin_amdgcn_mfma_f32_16x16x32_bf16(af[i], bfr[j], acc[i][j], 0, 0, 0);
        __syncthreads();
    }

    const int cn = lane & 15;
    const int r4 = (lane >> 4) * 4;
    #pragma unroll
    for (int i = 0; i < 4; i++) {
        #pragma unroll
        for (int j = 0; j < JN; j++) {
            int row = bm + wm + i * 16 + r4;
            int col = bn + wn + j * 16 + cn;
            #pragma unroll
            for (int rr = 0; rr < 4; rr++) {
                float v = acc[i][j][rr];
                int rw = row + rr;
                if (EPI == 0) {
                    ((bf16*)Cout)[(size_t)rw * ldc + col] = f2b(v);
                } else if (EPI == 1) {
                    if (col < 2048) {
                        v += extra[col];
                        float sp = (v > 15.f) ? v : log1pf(__expf(v));
                        ((float*)Cout)[(size_t)rw * ldc + col] = sp;
                    } else if (col < 2064) {
                        Bqp[(size_t)rw * 16 + (col - 2048)] = v;
                    } else if (col < 2080) {
                        Cqp[(size_t)rw * 16 + (col - 2064)] = v;
                    }
                } else {
                    v += extra[(size_t)rw * ldc + col];
                    ((float*)Cout)[(size_t)rw * ldc + col] = v;
                }
            }
        }
    }
}

// ---------------------------------------------------------------- depthwise causal conv + SiLU
__global__ __launch_bounds__(256) void conv_kernel(const bf16* __restrict__ xz,
                                                   const float* __restrict__ wconv,
                                                   const float* __restrict__ bconv,
                                                   bf16* __restrict__ xs) {
    int d = blockIdx.x * 256 + threadIdx.x;
    int b = blockIdx.z;
    int l0 = blockIdx.y * 128;
    float w0 = wconv[d * 4 + 0];
    float w1 = wconv[d * 4 + 1];
    float w2 = wconv[d * 4 + 2];
    float w3 = wconv[d * 4 + 3];
    float bc = bconv[d];
    const bf16* base = xz + (size_t)(b * L_) * (2 * DIN) + d;
    float xm3 = (l0 >= 3) ? b2f(base[(size_t)(l0 - 3) * (2 * DIN)]) : 0.f;
    float xm2 = (l0 >= 2) ? b2f(base[(size_t)(l0 - 2) * (2 * DIN)]) : 0.f;
    float xm1 = (l0 >= 1) ? b2f(base[(size_t)(l0 - 1) * (2 * DIN)]) : 0.f;
    for (int l = l0; l < l0 + 128; ++l) {
        float cur = b2f(base[(size_t)l * (2 * DIN)]);
        float v = fmaf(w0, xm3, fmaf(w1, xm2, fmaf(w2, xm1, fmaf(w3, cur, bc))));
        float s = v / (1.f + __expf(-v));
        xs[(size_t)(b * L_ + l) * DIN + d] = f2b(s);
        xm3 = xm2; xm2 = xm1; xm1 = cur;
    }
}

// ---------------------------------------------------------------- chunked selective scan
__global__ __launch_bounds__(256) void scan_passA(const float* __restrict__ delta,
                                                  const bf16* __restrict__ xs,
                                                  const float* __restrict__ Bq,
                                                  const float* __restrict__ A_log,
                                                  float* __restrict__ hend,
                                                  float* __restrict__ aprod) {
    __shared__ float Bsh[CH * 16];
    const int d = blockIdx.x * 256 + threadIdx.x;
    const int c = blockIdx.y, b = blockIdx.z;
    const int t0 = b * L_ + c * CH;
    for (int i = threadIdx.x; i < CH * 16; i += 256)
        Bsh[i] = Bq[(size_t)t0 * 16 + i];
    float A[NST], h[NST], ap[NST];
    {
        const float4* al = (const float4*)(A_log + d * 16);
        #pragma unroll
        for (int q = 0; q < 4; q++) {
            float4 v = al[q];
            A[q * 4 + 0] = -__expf(v.x); A[q * 4 + 1] = -__expf(v.y);
            A[q * 4 + 2] = -__expf(v.z); A[q * 4 + 3] = -__expf(v.w);
        }
    }
    #pragma unroll
    for (int n = 0; n < NST; n++) { h[n] = 0.f; ap[n] = 1.f; }
    __syncthreads();
    for (int tt = 0; tt < CH; ++tt) {
        int t = t0 + tt;
        float dlt = delta[(size_t)t * DIN + d];
        float dx = dlt * b2f(xs[(size_t)t * DIN + d]);
        #pragma unroll
        for (int n = 0; n < NST; n++) {
            float a = __expf(dlt * A[n]);
            h[n] = fmaf(a, h[n], dx * Bsh[tt * 16 + n]);
            ap[n] *= a;
        }
    }
    size_t base = ((size_t)(b * NCH + c) * DIN + d) * 16;
    #pragma unroll
    for (int q = 0; q < 4; q++) {
        ((float4*)(hend + base))[q]  = (float4){h[q*4], h[q*4+1], h[q*4+2], h[q*4+3]};
        ((float4*)(aprod + base))[q] = (float4){ap[q*4], ap[q*4+1], ap[q*4+2], ap[q*4+3]};
    }
}

__global__ __launch_bounds__(256) void scan_passB(const float* __restrict__ hend,
                                                  const float* __restrict__ aprod,
                                                  float* __restrict__ hinit) {
    int tid = blockIdx.x * 256 + threadIdx.x;
    int b = tid >> 15;
    int dn = tid & 32767;
    float h = 0.f;
    size_t base = (size_t)b * NCH * DIN * 16 + dn;
    for (int c = 0; c < NCH; ++c) {
        size_t idx = base + (size_t)c * DIN * 16;
        hinit[idx] = h;
        h = fmaf(aprod[idx], h, hend[idx]);
    }
}

__global__ __launch_bounds__(256) void scan_passC(const float* __restrict__ delta,
                                                  const bf16* __restrict__ xs,
                                                  const float* __restrict__ Bq,
                                                  const float* __restrict__ Cq,
                                                  const float* __restrict__ A_log,
                                                  const float* __restrict__ Dp,
                                                  const bf16* __restrict__ xz,
                                                  const float* __restrict__ hinit,
                                                  bf16* __restrict__ gbuf) {
    __shared__ float Bsh[CH * 16];
    __shared__ float Csh[CH * 16];
    const int d = blockIdx.x * 256 + threadIdx.x;
    const int c = blockIdx.y, b = blockIdx.z;
    const int t0 = b * L_ + c * CH;
    for (int i = threadIdx.x; i < CH * 16; i += 256) {
        Bsh[i] = Bq[(size_t)t0 * 16 + i];
        Csh[i] = Cq[(size_t)t0 * 16 + i];
    }
    float A[NST], h[NST];
    {
        const float4* al = (const float4*)(A_log + d * 16);
        #pragma unroll
        for (int q = 0; q < 4; q++) {
            float4 v = al[q];
            A[q * 4 + 0] = -__expf(v.x); A[q * 4 + 1] = -__expf(v.y);
            A[q * 4 + 2] = -__expf(v.z); A[q * 4 + 3] = -__expf(v.w);
        }
    }
    {
        size_t base = ((size_t)(b * NCH + c) * DIN + d) * 16;
        #pragma unroll
        for (int q = 0; q < 4; q++) {
            float4 v = ((const float4*)(hinit + base))[q];
            h[q * 4 + 0] = v.x; h[q * 4 + 1] = v.y; h[q * 4 + 2] = v.z; h[q * 4 + 3] = v.w;
        }
    }
    float Dd = Dp[d];
    __syncthreads();
    for (int tt = 0; tt < CH; ++tt) {
        int t = t0 + tt;
        float dlt = delta[(size_t)t * DIN + d];
        float xv = b2f(xs[(size_t)t * DIN + d]);
        float dx = dlt * xv;
        float y = Dd * xv;
        #pragma unroll
        for (int n = 0; n < NST; n++) {
            float a = __expf(dlt * A[n]);
            h[n] = fmaf(a, h[n], dx * Bsh[tt * 16 + n]);
            y = fmaf(h[n], Csh[tt * 16 + n], y);
        }
        float zv = b2f(xz[(size_t)t * (2 * DIN) + DIN + d]);
        float gg = y * (zv / (1.f + __expf(-zv)));
        gbuf[(size_t)t * DIN + d] = f2b(gg);
    }
}

// ---------------------------------------------------------------- launch
extern "C" void kernel_launch(void* const* d_in, const int* in_sizes, int n_in,
                              void* d_out, int out_size, void* d_ws, size_t ws_size,
                              hipStream_t stream) {
    const float* x       = (const float*)d_in[0];
    const float* w_norm  = (const float*)d_in[1];
    const float* b_norm  = (const float*)d_in[2];
    const float* w_in    = (const float*)d_in[3];
    const float* w_conv  = (const float*)d_in[4];
    const float* b_conv  = (const float*)d_in[5];
    const float* A_log   = (const float*)d_in[6];
    const float* w_b     = (const float*)d_in[7];
    const float* w_c     = (const float*)d_in[8];
    const float* w_delta = (const float*)d_in[9];
    const float* b_delta = (const float*)d_in[10];
    const float* D_param = (const float*)d_in[11];
    const float* w_out   = (const float*)d_in[12];
    float* out = (float*)d_out;

    char* p = (char*)d_ws;
    if (ws_size < WS_NEEDED) {
        void* sp = nullptr;
        hipGetSymbolAddress(&sp, HIP_SYMBOL(g_scratch));
        p = (char*)sp;
    }
    auto alloc = [&](size_t bytes) { char* q = p; p += (bytes + 255) & ~255ull; return q; };

    bf16* wT_in    = (bf16*)alloc((size_t)4096 * 1024 * 2);
    bf16* wT_dbc   = (bf16*)alloc((size_t)NEXT * 2048 * 2);   // delta + B/C extended weight
    bf16* wT_out   = (bf16*)alloc((size_t)1024 * 2048 * 2);
    bf16* xn       = (bf16*)alloc((size_t)T_ * D_ * 2);
    bf16* xz       = (bf16*)alloc((size_t)T_ * 2 * DIN * 2);
    bf16* xs       = (bf16*)alloc((size_t)T_ * DIN * 2);
    float* delta   = (float*)alloc((size_t)T_ * DIN * 4);
    float* Bq      = (float*)alloc((size_t)T_ * NST * 4);
    float* Cq      = (float*)alloc((size_t)T_ * NST * 4);
    bf16* gbuf     = (bf16*)alloc((size_t)T_ * DIN * 2);
    float* hend    = (float*)alloc((size_t)B_ * NCH * DIN * NST * 4);
    float* aprod   = (float*)alloc((size_t)B_ * NCH * DIN * NST * 4);
    float* hinit   = (float*)alloc((size_t)B_ * NCH * DIN * NST * 4);

    transpose_f2b<<<dim3(4096 / 32, 1024 / 32), 256, 0, stream>>>(w_in, wT_in, 1024, 4096);
    transpose_f2b<<<dim3(2048 / 32, 2048 / 32), 256, 0, stream>>>(w_delta, wT_dbc, 2048, 2048);
    bcw_prep<<<dim3(2048 / 256, 128), 256, 0, stream>>>(w_b, w_c, wT_dbc);
    transpose_f2b<<<dim3(1024 / 32, 2048 / 32), 256, 0, stream>>>(w_out, wT_out, 2048, 1024);

    ln_kernel<<<T_, 256, 0, stream>>>(x, w_norm, b_norm, xn);

    // xz = xn @ w_in  (M=4096, N=4096, K=1024), NT=128, 1024 blocks
    gemm128<0, 128><<<dim3(4096 / 128, T_ / 128), 256, 0, stream>>>(
        xn, wT_in, 1024, xz, nullptr, 4096, nullptr, nullptr);

    conv_kernel<<<dim3(DIN / 256, L_ / 128, B_), 256, 0, stream>>>(xz, w_conv, b_conv, xs);

    // delta+Bq+Cq = xs @ [w_delta | w_b | w_c]  (M=4096, N=2176, K=2048), NT=64, 1088 blocks
    gemm128<1, 64><<<dim3(NEXT / 64, T_ / 128), 256, 0, stream>>>(
        xs, wT_dbc, 2048, delta, b_delta, 2048, Bq, Cq);

    scan_passA<<<dim3(DIN / 256, NCH, B_), 256, 0, stream>>>(delta, xs, Bq, A_log, hend, aprod);
    scan_passB<<<(B_ * DIN * NST) / 256, 256, 0, stream>>>(hend, aprod, hinit);
    scan_passC<<<dim3(DIN / 256, NCH, B_), 256, 0, stream>>>(delta, xs, Bq, Cq, A_log, D_param,
                                                             xz, hinit, gbuf);

    // out = gbuf @ w_out + residual  (M=4096, N=1024, K=2048), NT=64, 512 blocks
    gemm128<2, 64><<<dim3(1024 / 64, T_ / 128), 256, 0, stream>>>(
        gbuf, wT_out, 2048, out, x, 1024, nullptr, nullptr);
}

// Round 8
// 441.372 us; speedup vs baseline: 1.0496x; 1.0496x over previous
//
#include <hip/hip_runtime.h>
#include <hip/hip_bf16.h>

typedef __hip_bfloat16 bf16;
typedef __bf16 bf16x8 __attribute__((ext_vector_type(8)));
typedef float f32x4 __attribute__((ext_vector_type(4)));

#define B_  2
#define L_  2048
#define D_  1024
#define DIN 2048
#define NST 16
#define T_  (B_ * L_)   // 4096 tokens
#define NCH 32          // scan chunks per sequence
#define CH  64          // tokens per chunk
#define NEXT 2176       // DIN + 128 fused B/C columns for gemm<1>

// Static fallback scratch if harness d_ws is too small (~228 MiB needed).
#define WS_NEEDED 229000000ull
__device__ __align__(256) char g_scratch[251658240];   // 240 MiB

__device__ __forceinline__ float b2f(bf16 v) { return __bfloat162float(v); }
__device__ __forceinline__ bf16 f2b(float v) { return __float2bfloat16(v); }

__device__ __forceinline__ void async16(const bf16* g, bf16* l) {
    __builtin_amdgcn_global_load_lds((const __attribute__((address_space(1))) unsigned int*)g,
                                     (__attribute__((address_space(3))) unsigned int*)l, 16, 0, 0);
}

// ---------------------------------------------------------------- transpose + fp32->bf16
__global__ __launch_bounds__(256) void transpose_f2b(const float* __restrict__ in,
                                                     bf16* __restrict__ out, int R, int C) {
    __shared__ float t[32][33];
    int c0 = blockIdx.x * 32, r0 = blockIdx.y * 32;
    int tx = threadIdx.x & 31, ty = threadIdx.x >> 5;
    #pragma unroll
    for (int i = 0; i < 32; i += 8)
        t[ty + i][tx] = in[(size_t)(r0 + ty + i) * C + c0 + tx];
    __syncthreads();
    #pragma unroll
    for (int i = 0; i < 32; i += 8)
        out[(size_t)(c0 + ty + i) * R + r0 + tx] = f2b(t[tx][ty + i]);
}

// ---------------------------------------------------------------- w_b/w_c rows of extended weight
__global__ __launch_bounds__(256) void bcw_prep(const float* __restrict__ wb,
                                                const float* __restrict__ wc,
                                                bf16* __restrict__ dst) {
    int k = blockIdx.x * 256 + threadIdx.x;   // 0..2047
    int rn = blockIdx.y;                       // 0..127
    float v = 0.f;
    if (rn < 16) v = wb[(size_t)k * 16 + rn];
    else if (rn < 32) v = wc[(size_t)k * 16 + (rn - 16)];
    dst[(size_t)(2048 + rn) * 2048 + k] = f2b(v);
}

// ---------------------------------------------------------------- layernorm (fp32 in, bf16 out)
__global__ __launch_bounds__(256) void ln_kernel(const float* __restrict__ x,
                                                 const float* __restrict__ w,
                                                 const float* __restrict__ bb,
                                                 bf16* __restrict__ xn) {
    int tok = blockIdx.x, tid = threadIdx.x;
    const float* xr = x + (size_t)tok * D_;
    float4 v4 = ((const float4*)xr)[tid];
    float v[4] = {v4.x, v4.y, v4.z, v4.w};
    float s = 0.f, ss = 0.f;
    #pragma unroll
    for (int i = 0; i < 4; i++) { s += v[i]; ss += v[i] * v[i]; }
    #pragma unroll
    for (int o = 32; o > 0; o >>= 1) { s += __shfl_down(s, o); ss += __shfl_down(ss, o); }
    __shared__ float rs[4], rss[4], mv[2];
    if ((tid & 63) == 0) { rs[tid >> 6] = s; rss[tid >> 6] = ss; }
    __syncthreads();
    if (tid == 0) {
        float S = rs[0] + rs[1] + rs[2] + rs[3];
        float SS = rss[0] + rss[1] + rss[2] + rss[3];
        float mu = S * (1.f / D_);
        float var = SS * (1.f / D_) - mu * mu;
        mv[0] = mu; mv[1] = rsqrtf(fmaxf(var, 0.f) + 1e-5f);
    }
    __syncthreads();
    float mu = mv[0], rstd = mv[1];
    float4 wv = ((const float4*)w)[tid];
    float4 bv = ((const float4*)bb)[tid];
    float wa[4] = {wv.x, wv.y, wv.z, wv.w};
    float ba[4] = {bv.x, bv.y, bv.z, bv.w};
    union { uint2 u; bf16 h[4]; } q;
    #pragma unroll
    for (int i = 0; i < 4; i++)
        q.h[i] = f2b((v[i] - mu) * rstd * wa[i] + ba[i]);
    ((uint2*)(xn + (size_t)tok * D_))[tid] = q.u;
}

// ---------------------------------------------------------------- GEMM 128x128 (m97), optional split-K
// C[M,N] = A[M,K] @ Bt[N,K]^T over K slice [z*K, (z+1)*K), z = blockIdx.z
// EPI 0: store bf16 | 3: store raw fp32 partial at Cout + z*partStride
template <int EPI>
__global__ __launch_bounds__(256) void gemm128(const bf16* __restrict__ A,
                                               const bf16* __restrict__ Bt,
                                               int K, int lda, int ldb,
                                               void* __restrict__ Cout, int ldc,
                                               size_t partStride) {
    __shared__ __align__(16) bf16 As[128 * 32];
    __shared__ __align__(16) bf16 Bs[128 * 32];
    const int tid = threadIdx.x;
    const int lane = tid & 63;
    const int wave = tid >> 6;
    const int bm = blockIdx.y * 128, bn = blockIdx.x * 128;
    const int wm = (wave & 1) * 64, wn = (wave >> 1) * 64;
    const int kz = blockIdx.z * K;
    f32x4 acc[4][4];
    #pragma unroll
    for (int i = 0; i < 4; i++)
        #pragma unroll
        for (int j = 0; j < 4; j++) acc[i][j] = (f32x4){0.f, 0.f, 0.f, 0.f};

    const int r = tid >> 2;
    const int c = tid & 3;
    const bf16* ga  = A  + (size_t)(bm + r) * lda + kz + c * 8;
    const bf16* gb  = Bt + (size_t)(bn + r) * ldb + kz + c * 8;
    const bf16* ga2 = ga + (size_t)64 * lda;
    const bf16* gb2 = gb + (size_t)64 * ldb;
    bf16* la  = As + tid * 8;           // wave-uniform base + lane*16B
    bf16* lb  = Bs + tid * 8;
    bf16* la2 = la + 64 * 32;
    bf16* lb2 = lb + 64 * 32;

    const int fm = lane & 15;
    const int fk = (lane >> 4) * 8;

    for (int k0 = 0; k0 < K; k0 += 32) {
        async16(ga + k0, la);
        async16(ga2 + k0, la2);
        async16(gb + k0, lb);
        async16(gb2 + k0, lb2);
        __syncthreads();
        bf16x8 af[4], bfr[4];
        #pragma unroll
        for (int i = 0; i < 4; i++)
            af[i] = *(const bf16x8*)(As + (wm + i * 16 + fm) * 32 + fk);
        #pragma unroll
        for (int j = 0; j < 4; j++)
            bfr[j] = *(const bf16x8*)(Bs + (wn + j * 16 + fm) * 32 + fk);
        #pragma unroll
        for (int i = 0; i < 4; i++)
            #pragma unroll
            for (int j = 0; j < 4; j++)
                acc[i][j] = __builtin_amdgcn_mfma_f32_16x16x32_bf16(af[i], bfr[j], acc[i][j], 0, 0, 0);
        __syncthreads();
    }

    const int cn = lane & 15;
    const int r4 = (lane >> 4) * 4;
    float* Cp = (float*)Cout + (size_t)blockIdx.z * partStride;
    #pragma unroll
    for (int i = 0; i < 4; i++) {
        #pragma unroll
        for (int j = 0; j < 4; j++) {
            int row = bm + wm + i * 16 + r4;
            int col = bn + wn + j * 16 + cn;
            #pragma unroll
            for (int rr = 0; rr < 4; rr++) {
                float v = acc[i][j][rr];
                size_t idx = (size_t)(row + rr) * ldc + col;
                if (EPI == 0) ((bf16*)Cout)[idx] = f2b(v);
                else          Cp[idx] = v;
            }
        }
    }
}

// ---------------------------------------------------------------- split-K combines
// P holds 2 partials of (T_, NEXT). cols<2048: +bias, softplus -> delta; 2048..2079 -> Bq/Cq
__global__ __launch_bounds__(256) void combine1(const float* __restrict__ P,
                                                const float* __restrict__ bias,
                                                float* __restrict__ delta,
                                                float* __restrict__ Bq,
                                                float* __restrict__ Cq) {
    const int NF = NEXT / 4;   // 544
    int i = blockIdx.x * 256 + threadIdx.x;
    if (i >= T_ * NF) return;
    int row = i / NF;
    int col = (i - row * NF) * 4;
    float4 a = ((const float4*)P)[i];
    float4 b = ((const float4*)(P + (size_t)T_ * NEXT))[i];
    float v[4] = {a.x + b.x, a.y + b.y, a.z + b.z, a.w + b.w};
    if (col < 2048) {
        const float* bs = bias + col;
        float o[4];
        #pragma unroll
        for (int j = 0; j < 4; j++) {
            float u = v[j] + bs[j];
            o[j] = (u > 15.f) ? u : log1pf(__expf(u));
        }
        *(float4*)(delta + (size_t)row * 2048 + col) = (float4){o[0], o[1], o[2], o[3]};
    } else if (col < 2064) {
        *(float4*)(Bq + (size_t)row * 16 + (col - 2048)) = (float4){v[0], v[1], v[2], v[3]};
    } else if (col < 2080) {
        *(float4*)(Cq + (size_t)row * 16 + (col - 2064)) = (float4){v[0], v[1], v[2], v[3]};
    }
}

// P holds 4 partials of (T_, D_). out = sum + residual x
__global__ __launch_bounds__(256) void combine2(const float* __restrict__ P,
                                                const float* __restrict__ x,
                                                float* __restrict__ out) {
    int i = blockIdx.x * 256 + threadIdx.x;   // over T_*D_/4
    const size_t ps = (size_t)T_ * D_;
    float4 a = ((const float4*)P)[i];
    float4 b = ((const float4*)(P + ps))[i];
    float4 c = ((const float4*)(P + 2 * ps))[i];
    float4 d = ((const float4*)(P + 3 * ps))[i];
    float4 xr = ((const float4*)x)[i];
    float4 o = {a.x + b.x + c.x + d.x + xr.x, a.y + b.y + c.y + d.y + xr.y,
                a.z + b.z + c.z + d.z + xr.z, a.w + b.w + c.w + d.w + xr.w};
    ((float4*)out)[i] = o;
}

// ---------------------------------------------------------------- depthwise causal conv + SiLU
__global__ __launch_bounds__(256) void conv_kernel(const bf16* __restrict__ xz,
                                                   const float* __restrict__ wconv,
                                                   const float* __restrict__ bconv,
                                                   bf16* __restrict__ xs) {
    int d = blockIdx.x * 256 + threadIdx.x;
    int b = blockIdx.z;
    int l0 = blockIdx.y * 128;
    float w0 = wconv[d * 4 + 0];
    float w1 = wconv[d * 4 + 1];
    float w2 = wconv[d * 4 + 2];
    float w3 = wconv[d * 4 + 3];
    float bc = bconv[d];
    const bf16* base = xz + (size_t)(b * L_) * (2 * DIN) + d;
    float xm3 = (l0 >= 3) ? b2f(base[(size_t)(l0 - 3) * (2 * DIN)]) : 0.f;
    float xm2 = (l0 >= 2) ? b2f(base[(size_t)(l0 - 2) * (2 * DIN)]) : 0.f;
    float xm1 = (l0 >= 1) ? b2f(base[(size_t)(l0 - 1) * (2 * DIN)]) : 0.f;
    for (int l = l0; l < l0 + 128; ++l) {
        float cur = b2f(base[(size_t)l * (2 * DIN)]);
        float v = fmaf(w0, xm3, fmaf(w1, xm2, fmaf(w2, xm1, fmaf(w3, cur, bc))));
        float s = v / (1.f + __expf(-v));
        xs[(size_t)(b * L_ + l) * DIN + d] = f2b(s);
        xm3 = xm2; xm2 = xm1; xm1 = cur;
    }
}

// ---------------------------------------------------------------- chunked selective scan
__global__ __launch_bounds__(256) void scan_passA(const float* __restrict__ delta,
                                                  const bf16* __restrict__ xs,
                                                  const float* __restrict__ Bq,
                                                  const float* __restrict__ A_log,
                                                  float* __restrict__ hend,
                                                  float* __restrict__ aprod) {
    __shared__ float Bsh[CH * 16];
    const int d = blockIdx.x * 256 + threadIdx.x;
    const int c = blockIdx.y, b = blockIdx.z;
    const int t0 = b * L_ + c * CH;
    for (int i = threadIdx.x; i < CH * 16; i += 256)
        Bsh[i] = Bq[(size_t)t0 * 16 + i];
    float A[NST], h[NST], ap[NST];
    {
        const float4* al = (const float4*)(A_log + d * 16);
        #pragma unroll
        for (int q = 0; q < 4; q++) {
            float4 v = al[q];
            A[q * 4 + 0] = -__expf(v.x); A[q * 4 + 1] = -__expf(v.y);
            A[q * 4 + 2] = -__expf(v.z); A[q * 4 + 3] = -__expf(v.w);
        }
    }
    #pragma unroll
    for (int n = 0; n < NST; n++) { h[n] = 0.f; ap[n] = 1.f; }
    __syncthreads();
    for (int tt = 0; tt < CH; ++tt) {
        int t = t0 + tt;
        float dlt = delta[(size_t)t * DIN + d];
        float dx = dlt * b2f(xs[(size_t)t * DIN + d]);
        #pragma unroll
        for (int n = 0; n < NST; n++) {
            float a = __expf(dlt * A[n]);
            h[n] = fmaf(a, h[n], dx * Bsh[tt * 16 + n]);
            ap[n] *= a;
        }
    }
    size_t base = ((size_t)(b * NCH + c) * DIN + d) * 16;
    #pragma unroll
    for (int q = 0; q < 4; q++) {
        ((float4*)(hend + base))[q]  = (float4){h[q*4], h[q*4+1], h[q*4+2], h[q*4+3]};
        ((float4*)(aprod + base))[q] = (float4){ap[q*4], ap[q*4+1], ap[q*4+2], ap[q*4+3]};
    }
}

__global__ __launch_bounds__(256) void scan_passB(const float* __restrict__ hend,
                                                  const float* __restrict__ aprod,
                                                  float* __restrict__ hinit) {
    int tid = blockIdx.x * 256 + threadIdx.x;
    int b = tid >> 15;
    int dn = tid & 32767;
    float h = 0.f;
    size_t base = (size_t)b * NCH * DIN * 16 + dn;
    for (int c = 0; c < NCH; ++c) {
        size_t idx = base + (size_t)c * DIN * 16;
        hinit[idx] = h;
        h = fmaf(aprod[idx], h, hend[idx]);
    }
}

__global__ __launch_bounds__(256) void scan_passC(const float* __restrict__ delta,
                                                  const bf16* __restrict__ xs,
                                                  const float* __restrict__ Bq,
                                                  const float* __restrict__ Cq,
                                                  const float* __restrict__ A_log,
                                                  const float* __restrict__ Dp,
                                                  const bf16* __restrict__ xz,
                                                  const float* __restrict__ hinit,
                                                  bf16* __restrict__ gbuf) {
    __shared__ float Bsh[CH * 16];
    __shared__ float Csh[CH * 16];
    const int d = blockIdx.x * 256 + threadIdx.x;
    const int c = blockIdx.y, b = blockIdx.z;
    const int t0 = b * L_ + c * CH;
    for (int i = threadIdx.x; i < CH * 16; i += 256) {
        Bsh[i] = Bq[(size_t)t0 * 16 + i];
        Csh[i] = Cq[(size_t)t0 * 16 + i];
    }
    float A[NST], h[NST];
    {
        const float4* al = (const float4*)(A_log + d * 16);
        #pragma unroll
        for (int q = 0; q < 4; q++) {
            float4 v = al[q];
            A[q * 4 + 0] = -__expf(v.x); A[q * 4 + 1] = -__expf(v.y);
            A[q * 4 + 2] = -__expf(v.z); A[q * 4 + 3] = -__expf(v.w);
        }
    }
    {
        size_t base = ((size_t)(b * NCH + c) * DIN + d) * 16;
        #pragma unroll
        for (int q = 0; q < 4; q++) {
            float4 v = ((const float4*)(hinit + base))[q];
            h[q * 4 + 0] = v.x; h[q * 4 + 1] = v.y; h[q * 4 + 2] = v.z; h[q * 4 + 3] = v.w;
        }
    }
    float Dd = Dp[d];
    __syncthreads();
    for (int tt = 0; tt < CH; ++tt) {
        int t = t0 + tt;
        float dlt = delta[(size_t)t * DIN + d];
        float xv = b2f(xs[(size_t)t * DIN + d]);
        float dx = dlt * xv;
        float y = Dd * xv;
        #pragma unroll
        for (int n = 0; n < NST; n++) {
            float a = __expf(dlt * A[n]);
            h[n] = fmaf(a, h[n], dx * Bsh[tt * 16 + n]);
            y = fmaf(h[n], Csh[tt * 16 + n], y);
        }
        float zv = b2f(xz[(size_t)t * (2 * DIN) + DIN + d]);
        float gg = y * (zv / (1.f + __expf(-zv)));
        gbuf[(size_t)t * DIN + d] = f2b(gg);
    }
}

// ---------------------------------------------------------------- launch
extern "C" void kernel_launch(void* const* d_in, const int* in_sizes, int n_in,
                              void* d_out, int out_size, void* d_ws, size_t ws_size,
                              hipStream_t stream) {
    const float* x       = (const float*)d_in[0];
    const float* w_norm  = (const float*)d_in[1];
    const float* b_norm  = (const float*)d_in[2];
    const float* w_in    = (const float*)d_in[3];
    const float* w_conv  = (const float*)d_in[4];
    const float* b_conv  = (const float*)d_in[5];
    const float* A_log   = (const float*)d_in[6];
    const float* w_b     = (const float*)d_in[7];
    const float* w_c     = (const float*)d_in[8];
    const float* w_delta = (const float*)d_in[9];
    const float* b_delta = (const float*)d_in[10];
    const float* D_param = (const float*)d_in[11];
    const float* w_out   = (const float*)d_in[12];
    float* out = (float*)d_out;

    char* p = (char*)d_ws;
    if (ws_size < WS_NEEDED) {
        void* sp = nullptr;
        hipGetSymbolAddress(&sp, HIP_SYMBOL(g_scratch));
        p = (char*)sp;
    }
    auto alloc = [&](size_t bytes) { char* q = p; p += (bytes + 255) & ~255ull; return q; };

    bf16* wT_in    = (bf16*)alloc((size_t)4096 * 1024 * 2);
    bf16* wT_dbc   = (bf16*)alloc((size_t)NEXT * 2048 * 2);
    bf16* wT_out   = (bf16*)alloc((size_t)1024 * 2048 * 2);
    bf16* xn       = (bf16*)alloc((size_t)T_ * D_ * 2);
    bf16* xz       = (bf16*)alloc((size_t)T_ * 2 * DIN * 2);
    bf16* xs       = (bf16*)alloc((size_t)T_ * DIN * 2);
    float* delta   = (float*)alloc((size_t)T_ * DIN * 4);
    float* Bq      = (float*)alloc((size_t)T_ * NST * 4);
    float* Cq      = (float*)alloc((size_t)T_ * NST * 4);
    bf16* gbuf     = (bf16*)alloc((size_t)T_ * DIN * 2);
    float* hend    = (float*)alloc((size_t)B_ * NCH * DIN * NST * 4);
    float* aprod   = (float*)alloc((size_t)B_ * NCH * DIN * NST * 4);
    float* hinit   = (float*)alloc((size_t)B_ * NCH * DIN * NST * 4);
    float* P1      = (float*)alloc((size_t)2 * T_ * NEXT * 4);   // also aliased as P2 (4 x T_ x D_)
    float* P2      = P1;   // 4*T_*D_*4 = 67 MB <= 71 MB; P1 dead after combine1

    transpose_f2b<<<dim3(4096 / 32, 1024 / 32), 256, 0, stream>>>(w_in, wT_in, 1024, 4096);
    transpose_f2b<<<dim3(2048 / 32, 2048 / 32), 256, 0, stream>>>(w_delta, wT_dbc, 2048, 2048);
    bcw_prep<<<dim3(2048 / 256, 128), 256, 0, stream>>>(w_b, w_c, wT_dbc);
    transpose_f2b<<<dim3(1024 / 32, 2048 / 32), 256, 0, stream>>>(w_out, wT_out, 2048, 1024);

    ln_kernel<<<T_, 256, 0, stream>>>(x, w_norm, b_norm, xn);

    // xz = xn @ w_in  (M=4096, N=4096, K=1024), 1024 blocks
    gemm128<0><<<dim3(32, 32, 1), 256, 0, stream>>>(xn, wT_in, 1024, 1024, 1024,
                                                    xz, 4096, 0);

    conv_kernel<<<dim3(DIN / 256, L_ / 128, B_), 256, 0, stream>>>(xz, w_conv, b_conv, xs);

    // P1[z] = xs @ [w_delta|w_b|w_c] K-slice  (M=4096, N=2176, split-K=2), 1088 blocks
    gemm128<3><<<dim3(NEXT / 128, 32, 2), 256, 0, stream>>>(xs, wT_dbc, 1024, 2048, 2048,
                                                            P1, NEXT, (size_t)T_ * NEXT);
    combine1<<<(T_ * (NEXT / 4) + 255) / 256, 256, 0, stream>>>(P1, b_delta, delta, Bq, Cq);

    scan_passA<<<dim3(DIN / 256, NCH, B_), 256, 0, stream>>>(delta, xs, Bq, A_log, hend, aprod);
    scan_passB<<<(B_ * DIN * NST) / 256, 256, 0, stream>>>(hend, aprod, hinit);
    scan_passC<<<dim3(DIN / 256, NCH, B_), 256, 0, stream>>>(delta, xs, Bq, Cq, A_log, D_param,
                                                             xz, hinit, gbuf);

    // P2[z] = gbuf @ w_out K-slice  (M=4096, N=1024, split-K=4), 1024 blocks
    gemm128<3><<<dim3(8, 32, 4), 256, 0, stream>>>(gbuf, wT_out, 512, 2048, 2048,
                                                   P2, 1024, (size_t)T_ * D_);
    combine2<<<(T_ * D_ / 4) / 256, 256, 0, stream>>>(P2, x, out);
}

// Round 9
// 427.961 us; speedup vs baseline: 1.0825x; 1.0313x over previous
//
#include <hip/hip_runtime.h>
#include <hip/hip_bf16.h>

typedef __hip_bfloat16 bf16;
typedef __bf16 bf16x8 __attribute__((ext_vector_type(8)));
typedef float f32x4 __attribute__((ext_vector_type(4)));

#define B_  2
#define L_  2048
#define D_  1024
#define DIN 2048
#define NST 16
#define T_  (B_ * L_)   // 4096 tokens
#define NCH 32          // scan chunks per sequence
#define CH  64          // tokens per chunk
#define NEXT 2176       // DIN + 128 fused B/C columns for gemm<1>

// Static fallback scratch if harness d_ws is too small (~212 MiB needed).
#define WS_NEEDED 213000000ull
__device__ __align__(256) char g_scratch[234881024];   // 224 MiB

__device__ __forceinline__ float b2f(bf16 v) { return __bfloat162float(v); }
__device__ __forceinline__ bf16 f2b(float v) { return __float2bfloat16(v); }

__device__ __forceinline__ void async16(const bf16* g, bf16* l) {
    __builtin_amdgcn_global_load_lds((const __attribute__((address_space(1))) unsigned int*)g,
                                     (__attribute__((address_space(3))) unsigned int*)l, 16, 0, 0);
}

// ---------------------------------------------------------------- transpose + fp32->bf16
__global__ __launch_bounds__(256) void transpose_f2b(const float* __restrict__ in,
                                                     bf16* __restrict__ out, int R, int C) {
    __shared__ float t[32][33];
    int c0 = blockIdx.x * 32, r0 = blockIdx.y * 32;
    int tx = threadIdx.x & 31, ty = threadIdx.x >> 5;
    #pragma unroll
    for (int i = 0; i < 32; i += 8)
        t[ty + i][tx] = in[(size_t)(r0 + ty + i) * C + c0 + tx];
    __syncthreads();
    #pragma unroll
    for (int i = 0; i < 32; i += 8)
        out[(size_t)(c0 + ty + i) * R + r0 + tx] = f2b(t[tx][ty + i]);
}

// ---------------------------------------------------------------- w_b/w_c rows of extended weight
__global__ __launch_bounds__(256) void bcw_prep(const float* __restrict__ wb,
                                                const float* __restrict__ wc,
                                                bf16* __restrict__ dst) {
    int k = blockIdx.x * 256 + threadIdx.x;   // 0..2047
    int rn = blockIdx.y;                       // 0..127
    float v = 0.f;
    if (rn < 16) v = wb[(size_t)k * 16 + rn];
    else if (rn < 32) v = wc[(size_t)k * 16 + (rn - 16)];
    dst[(size_t)(2048 + rn) * 2048 + k] = f2b(v);
}

// ---------------------------------------------------------------- layernorm (fp32 in, bf16 out)
__global__ __launch_bounds__(256) void ln_kernel(const float* __restrict__ x,
                                                 const float* __restrict__ w,
                                                 const float* __restrict__ bb,
                                                 bf16* __restrict__ xn) {
    int tok = blockIdx.x, tid = threadIdx.x;
    const float* xr = x + (size_t)tok * D_;
    float4 v4 = ((const float4*)xr)[tid];
    float v[4] = {v4.x, v4.y, v4.z, v4.w};
    float s = 0.f, ss = 0.f;
    #pragma unroll
    for (int i = 0; i < 4; i++) { s += v[i]; ss += v[i] * v[i]; }
    #pragma unroll
    for (int o = 32; o > 0; o >>= 1) { s += __shfl_down(s, o); ss += __shfl_down(ss, o); }
    __shared__ float rs[4], rss[4], mv[2];
    if ((tid & 63) == 0) { rs[tid >> 6] = s; rss[tid >> 6] = ss; }
    __syncthreads();
    if (tid == 0) {
        float S = rs[0] + rs[1] + rs[2] + rs[3];
        float SS = rss[0] + rss[1] + rss[2] + rss[3];
        float mu = S * (1.f / D_);
        float var = SS * (1.f / D_) - mu * mu;
        mv[0] = mu; mv[1] = rsqrtf(fmaxf(var, 0.f) + 1e-5f);
    }
    __syncthreads();
    float mu = mv[0], rstd = mv[1];
    float4 wv = ((const float4*)w)[tid];
    float4 bv = ((const float4*)bb)[tid];
    float wa[4] = {wv.x, wv.y, wv.z, wv.w};
    float ba[4] = {bv.x, bv.y, bv.z, bv.w};
    union { uint2 u; bf16 h[4]; } q;
    #pragma unroll
    for (int i = 0; i < 4; i++)
        q.h[i] = f2b((v[i] - mu) * rstd * wa[i] + ba[i]);
    ((uint2*)(xn + (size_t)tok * D_))[tid] = q.u;
}

// ---------------------------------------------------------------- GEMM 128x128 (m97), split-K capable
// C[M,N] = A[M,K] @ Bt[N,K]^T over K slice [z*K,(z+1)*K)
// XCD swizzle: id%8 = XCD (HW round-robin) -> each XCD owns a 4-row-band strip,
// col-major within strip: A-strip (1 MB) stays L2-resident, B streams once per XCD.
// EPI 0: store bf16 | 3: store raw fp32 partial at Cout + z*partStride
template <int EPI>
__global__ __launch_bounds__(256) void gemm128(const bf16* __restrict__ A,
                                               const bf16* __restrict__ Bt,
                                               int K, int lda, int ldb,
                                               void* __restrict__ Cout, int ldc,
                                               size_t partStride) {
    __shared__ __align__(16) bf16 As[128 * 32];
    __shared__ __align__(16) bf16 Bs[128 * 32];
    const int tid = threadIdx.x;
    const int lane = tid & 63;
    const int wave = tid >> 6;
    // ---- XCD-aware tile remap (requires gridDim.y == 32) ----
    int id = blockIdx.y * gridDim.x + blockIdx.x;
    int xcd = id & 7;
    int t8 = id >> 3;
    int byi = xcd * 4 + (t8 & 3);
    int bxi = t8 >> 2;
    const int bm = byi * 128, bn = bxi * 128;
    const int wm = (wave & 1) * 64, wn = (wave >> 1) * 64;
    const int kz = blockIdx.z * K;
    f32x4 acc[4][4];
    #pragma unroll
    for (int i = 0; i < 4; i++)
        #pragma unroll
        for (int j = 0; j < 4; j++) acc[i][j] = (f32x4){0.f, 0.f, 0.f, 0.f};

    const int r = tid >> 2;
    const int c = tid & 3;
    const bf16* ga  = A  + (size_t)(bm + r) * lda + kz + c * 8;
    const bf16* gb  = Bt + (size_t)(bn + r) * ldb + kz + c * 8;
    const bf16* ga2 = ga + (size_t)64 * lda;
    const bf16* gb2 = gb + (size_t)64 * ldb;
    bf16* la  = As + tid * 8;           // wave-uniform base + lane*16B
    bf16* lb  = Bs + tid * 8;
    bf16* la2 = la + 64 * 32;
    bf16* lb2 = lb + 64 * 32;

    const int fm = lane & 15;
    const int fk = (lane >> 4) * 8;

    for (int k0 = 0; k0 < K; k0 += 32) {
        async16(ga + k0, la);
        async16(ga2 + k0, la2);
        async16(gb + k0, lb);
        async16(gb2 + k0, lb2);
        __syncthreads();
        bf16x8 af[4], bfr[4];
        #pragma unroll
        for (int i = 0; i < 4; i++)
            af[i] = *(const bf16x8*)(As + (wm + i * 16 + fm) * 32 + fk);
        #pragma unroll
        for (int j = 0; j < 4; j++)
            bfr[j] = *(const bf16x8*)(Bs + (wn + j * 16 + fm) * 32 + fk);
        #pragma unroll
        for (int i = 0; i < 4; i++)
            #pragma unroll
            for (int j = 0; j < 4; j++)
                acc[i][j] = __builtin_amdgcn_mfma_f32_16x16x32_bf16(af[i], bfr[j], acc[i][j], 0, 0, 0);
        __syncthreads();
    }

    const int cn = lane & 15;
    const int r4 = (lane >> 4) * 4;
    float* Cp = (float*)Cout + (size_t)blockIdx.z * partStride;
    #pragma unroll
    for (int i = 0; i < 4; i++) {
        #pragma unroll
        for (int j = 0; j < 4; j++) {
            int row = bm + wm + i * 16 + r4;
            int col = bn + wn + j * 16 + cn;
            #pragma unroll
            for (int rr = 0; rr < 4; rr++) {
                float v = acc[i][j][rr];
                size_t idx = (size_t)(row + rr) * ldc + col;
                if (EPI == 0) ((bf16*)Cout)[idx] = f2b(v);
                else          Cp[idx] = v;
            }
        }
    }
}

// ---------------------------------------------------------------- split-K combines
// P holds 2 partials of (T_, NEXT). cols<2048: +bias, softplus -> delta(bf16); 2048..2079 -> Bq/Cq
__global__ __launch_bounds__(256) void combine1(const float* __restrict__ P,
                                                const float* __restrict__ bias,
                                                bf16* __restrict__ delta,
                                                float* __restrict__ Bq,
                                                float* __restrict__ Cq) {
    const int NF = NEXT / 4;   // 544
    int i = blockIdx.x * 256 + threadIdx.x;
    if (i >= T_ * NF) return;
    int row = i / NF;
    int col = (i - row * NF) * 4;
    float4 a = ((const float4*)P)[i];
    float4 b = ((const float4*)(P + (size_t)T_ * NEXT))[i];
    float v[4] = {a.x + b.x, a.y + b.y, a.z + b.z, a.w + b.w};
    if (col < 2048) {
        const float* bs = bias + col;
        union { uint2 u; bf16 h[4]; } o;
        #pragma unroll
        for (int j = 0; j < 4; j++) {
            float u = v[j] + bs[j];
            o.h[j] = f2b((u > 15.f) ? u : log1pf(__expf(u)));
        }
        *(uint2*)(delta + (size_t)row * 2048 + col) = o.u;
    } else if (col < 2064) {
        *(float4*)(Bq + (size_t)row * 16 + (col - 2048)) = (float4){v[0], v[1], v[2], v[3]};
    } else if (col < 2080) {
        *(float4*)(Cq + (size_t)row * 16 + (col - 2064)) = (float4){v[0], v[1], v[2], v[3]};
    }
}

// P holds 4 partials of (T_, D_). out = sum + residual x
__global__ __launch_bounds__(256) void combine2(const float* __restrict__ P,
                                                const float* __restrict__ x,
                                                float* __restrict__ out) {
    int i = blockIdx.x * 256 + threadIdx.x;   // over T_*D_/4
    const size_t ps = (size_t)T_ * D_;
    float4 a = ((const float4*)P)[i];
    float4 b = ((const float4*)(P + ps))[i];
    float4 c = ((const float4*)(P + 2 * ps))[i];
    float4 d = ((const float4*)(P + 3 * ps))[i];
    float4 xr = ((const float4*)x)[i];
    float4 o = {a.x + b.x + c.x + d.x + xr.x, a.y + b.y + c.y + d.y + xr.y,
                a.z + b.z + c.z + d.z + xr.z, a.w + b.w + c.w + d.w + xr.w};
    ((float4*)out)[i] = o;
}

// ---------------------------------------------------------------- depthwise causal conv + SiLU
// 32 tokens per block -> 1024 blocks (4/CU)
__global__ __launch_bounds__(256) void conv_kernel(const bf16* __restrict__ xz,
                                                   const float* __restrict__ wconv,
                                                   const float* __restrict__ bconv,
                                                   bf16* __restrict__ xs) {
    int d = blockIdx.x * 256 + threadIdx.x;
    int b = blockIdx.z;
    int l0 = blockIdx.y * 32;
    float w0 = wconv[d * 4 + 0];
    float w1 = wconv[d * 4 + 1];
    float w2 = wconv[d * 4 + 2];
    float w3 = wconv[d * 4 + 3];
    float bc = bconv[d];
    const bf16* base = xz + (size_t)(b * L_) * (2 * DIN) + d;
    float xm3 = (l0 >= 3) ? b2f(base[(size_t)(l0 - 3) * (2 * DIN)]) : 0.f;
    float xm2 = (l0 >= 2) ? b2f(base[(size_t)(l0 - 2) * (2 * DIN)]) : 0.f;
    float xm1 = (l0 >= 1) ? b2f(base[(size_t)(l0 - 1) * (2 * DIN)]) : 0.f;
    for (int l = l0; l < l0 + 32; ++l) {
        float cur = b2f(base[(size_t)l * (2 * DIN)]);
        float v = fmaf(w0, xm3, fmaf(w1, xm2, fmaf(w2, xm1, fmaf(w3, cur, bc))));
        float s = v / (1.f + __expf(-v));
        xs[(size_t)(b * L_ + l) * DIN + d] = f2b(s);
        xm3 = xm2; xm2 = xm1; xm1 = cur;
    }
}

// ---------------------------------------------------------------- chunked selective scan
__global__ __launch_bounds__(256) void scan_passA(const bf16* __restrict__ delta,
                                                  const bf16* __restrict__ xs,
                                                  const float* __restrict__ Bq,
                                                  const float* __restrict__ A_log,
                                                  float* __restrict__ hend,
                                                  float* __restrict__ aprod) {
    __shared__ float Bsh[CH * 16];
    const int d = blockIdx.x * 256 + threadIdx.x;
    const int c = blockIdx.y, b = blockIdx.z;
    const int t0 = b * L_ + c * CH;
    for (int i = threadIdx.x; i < CH * 16; i += 256)
        Bsh[i] = Bq[(size_t)t0 * 16 + i];
    float A[NST], h[NST], ap[NST];
    {
        const float4* al = (const float4*)(A_log + d * 16);
        #pragma unroll
        for (int q = 0; q < 4; q++) {
            float4 v = al[q];
            A[q * 4 + 0] = -__expf(v.x); A[q * 4 + 1] = -__expf(v.y);
            A[q * 4 + 2] = -__expf(v.z); A[q * 4 + 3] = -__expf(v.w);
        }
    }
    #pragma unroll
    for (int n = 0; n < NST; n++) { h[n] = 0.f; ap[n] = 1.f; }
    __syncthreads();
    for (int tt = 0; tt < CH; ++tt) {
        int t = t0 + tt;
        float dlt = b2f(delta[(size_t)t * DIN + d]);
        float dx = dlt * b2f(xs[(size_t)t * DIN + d]);
        #pragma unroll
        for (int n = 0; n < NST; n++) {
            float a = __expf(dlt * A[n]);
            h[n] = fmaf(a, h[n], dx * Bsh[tt * 16 + n]);
            ap[n] *= a;
        }
    }
    size_t base = ((size_t)(b * NCH + c) * DIN + d) * 16;
    #pragma unroll
    for (int q = 0; q < 4; q++) {
        ((float4*)(hend + base))[q]  = (float4){h[q*4], h[q*4+1], h[q*4+2], h[q*4+3]};
        ((float4*)(aprod + base))[q] = (float4){ap[q*4], ap[q*4+1], ap[q*4+2], ap[q*4+3]};
    }
}

__global__ __launch_bounds__(256) void scan_passB(const float* __restrict__ hend,
                                                  const float* __restrict__ aprod,
                                                  float* __restrict__ hinit) {
    int tid = blockIdx.x * 256 + threadIdx.x;
    int b = tid >> 15;
    int dn = tid & 32767;
    float h = 0.f;
    size_t base = (size_t)b * NCH * DIN * 16 + dn;
    for (int c = 0; c < NCH; ++c) {
        size_t idx = base + (size_t)c * DIN * 16;
        hinit[idx] = h;
        h = fmaf(aprod[idx], h, hend[idx]);
    }
}

__global__ __launch_bounds__(256) void scan_passC(const bf16* __restrict__ delta,
                                                  const bf16* __restrict__ xs,
                                                  const float* __restrict__ Bq,
                                                  const float* __restrict__ Cq,
                                                  const float* __restrict__ A_log,
                                                  const float* __restrict__ Dp,
                                                  const bf16* __restrict__ xz,
                                                  const float* __restrict__ hinit,
                                                  bf16* __restrict__ gbuf) {
    __shared__ float Bsh[CH * 16];
    __shared__ float Csh[CH * 16];
    const int d = blockIdx.x * 256 + threadIdx.x;
    const int c = blockIdx.y, b = blockIdx.z;
    const int t0 = b * L_ + c * CH;
    for (int i = threadIdx.x; i < CH * 16; i += 256) {
        Bsh[i] = Bq[(size_t)t0 * 16 + i];
        Csh[i] = Cq[(size_t)t0 * 16 + i];
    }
    float A[NST], h[NST];
    {
        const float4* al = (const float4*)(A_log + d * 16);
        #pragma unroll
        for (int q = 0; q < 4; q++) {
            float4 v = al[q];
            A[q * 4 + 0] = -__expf(v.x); A[q * 4 + 1] = -__expf(v.y);
            A[q * 4 + 2] = -__expf(v.z); A[q * 4 + 3] = -__expf(v.w);
        }
    }
    {
        size_t base = ((size_t)(b * NCH + c) * DIN + d) * 16;
        #pragma unroll
        for (int q = 0; q < 4; q++) {
            float4 v = ((const float4*)(hinit + base))[q];
            h[q * 4 + 0] = v.x; h[q * 4 + 1] = v.y; h[q * 4 + 2] = v.z; h[q * 4 + 3] = v.w;
        }
    }
    float Dd = Dp[d];
    __syncthreads();
    for (int tt = 0; tt < CH; ++tt) {
        int t = t0 + tt;
        float dlt = b2f(delta[(size_t)t * DIN + d]);
        float xv = b2f(xs[(size_t)t * DIN + d]);
        float dx = dlt * xv;
        float y = Dd * xv;
        #pragma unroll
        for (int n = 0; n < NST; n++) {
            float a = __expf(dlt * A[n]);
            h[n] = fmaf(a, h[n], dx * Bsh[tt * 16 + n]);
            y = fmaf(h[n], Csh[tt * 16 + n], y);
        }
        float zv = b2f(xz[(size_t)t * (2 * DIN) + DIN + d]);
        float gg = y * (zv / (1.f + __expf(-zv)));
        gbuf[(size_t)t * DIN + d] = f2b(gg);
    }
}

// ---------------------------------------------------------------- launch
extern "C" void kernel_launch(void* const* d_in, const int* in_sizes, int n_in,
                              void* d_out, int out_size, void* d_ws, size_t ws_size,
                              hipStream_t stream) {
    const float* x       = (const float*)d_in[0];
    const float* w_norm  = (const float*)d_in[1];
    const float* b_norm  = (const float*)d_in[2];
    const float* w_in    = (const float*)d_in[3];
    const float* w_conv  = (const float*)d_in[4];
    const float* b_conv  = (const float*)d_in[5];
    const float* A_log   = (const float*)d_in[6];
    const float* w_b     = (const float*)d_in[7];
    const float* w_c     = (const float*)d_in[8];
    const float* w_delta = (const float*)d_in[9];
    const float* b_delta = (const float*)d_in[10];
    const float* D_param = (const float*)d_in[11];
    const float* w_out   = (const float*)d_in[12];
    float* out = (float*)d_out;

    char* p = (char*)d_ws;
    if (ws_size < WS_NEEDED) {
        void* sp = nullptr;
        hipGetSymbolAddress(&sp, HIP_SYMBOL(g_scratch));
        p = (char*)sp;
    }
    auto alloc = [&](size_t bytes) { char* q = p; p += (bytes + 255) & ~255ull; return q; };

    bf16* wT_in    = (bf16*)alloc((size_t)4096 * 1024 * 2);
    bf16* wT_dbc   = (bf16*)alloc((size_t)NEXT * 2048 * 2);
    bf16* wT_out   = (bf16*)alloc((size_t)1024 * 2048 * 2);
    bf16* xn       = (bf16*)alloc((size_t)T_ * D_ * 2);
    bf16* xz       = (bf16*)alloc((size_t)T_ * 2 * DIN * 2);
    bf16* xs       = (bf16*)alloc((size_t)T_ * DIN * 2);
    bf16* delta    = (bf16*)alloc((size_t)T_ * DIN * 2);
    float* Bq      = (float*)alloc((size_t)T_ * NST * 4);
    float* Cq      = (float*)alloc((size_t)T_ * NST * 4);
    bf16* gbuf     = (bf16*)alloc((size_t)T_ * DIN * 2);
    float* hend    = (float*)alloc((size_t)B_ * NCH * DIN * NST * 4);
    float* aprod   = (float*)alloc((size_t)B_ * NCH * DIN * NST * 4);
    float* hinit   = (float*)alloc((size_t)B_ * NCH * DIN * NST * 4);
    float* P1      = (float*)alloc((size_t)2 * T_ * NEXT * 4);   // aliased as P2 (4 x T_ x D_)
    float* P2      = P1;   // 67 MB <= 71 MB; P1 dead after combine1

    transpose_f2b<<<dim3(4096 / 32, 1024 / 32), 256, 0, stream>>>(w_in, wT_in, 1024, 4096);
    transpose_f2b<<<dim3(2048 / 32, 2048 / 32), 256, 0, stream>>>(w_delta, wT_dbc, 2048, 2048);
    bcw_prep<<<dim3(2048 / 256, 128), 256, 0, stream>>>(w_b, w_c, wT_dbc);
    transpose_f2b<<<dim3(1024 / 32, 2048 / 32), 256, 0, stream>>>(w_out, wT_out, 2048, 1024);

    ln_kernel<<<T_, 256, 0, stream>>>(x, w_norm, b_norm, xn);

    // xz = xn @ w_in  (M=4096, N=4096, K=1024), 1024 blocks
    gemm128<0><<<dim3(32, 32, 1), 256, 0, stream>>>(xn, wT_in, 1024, 1024, 1024,
                                                    xz, 4096, 0);

    conv_kernel<<<dim3(DIN / 256, L_ / 32, B_), 256, 0, stream>>>(xz, w_conv, b_conv, xs);

    // P1[z] = xs @ [w_delta|w_b|w_c] K-slice  (M=4096, N=2176, split-K=2), 1088 blocks
    gemm128<3><<<dim3(NEXT / 128, 32, 2), 256, 0, stream>>>(xs, wT_dbc, 1024, 2048, 2048,
                                                            P1, NEXT, (size_t)T_ * NEXT);
    combine1<<<(T_ * (NEXT / 4) + 255) / 256, 256, 0, stream>>>(P1, b_delta, delta, Bq, Cq);

    scan_passA<<<dim3(DIN / 256, NCH, B_), 256, 0, stream>>>(delta, xs, Bq, A_log, hend, aprod);
    scan_passB<<<(B_ * DIN * NST) / 256, 256, 0, stream>>>(hend, aprod, hinit);
    scan_passC<<<dim3(DIN / 256, NCH, B_), 256, 0, stream>>>(delta, xs, Bq, Cq, A_log, D_param,
                                                             xz, hinit, gbuf);

    // P2[z] = gbuf @ w_out K-slice  (M=4096, N=1024, split-K=4), 1024 blocks
    gemm128<3><<<dim3(8, 32, 4), 256, 0, stream>>>(gbuf, wT_out, 512, 2048, 2048,
                                                   P2, 1024, (size_t)T_ * D_);
    combine2<<<(T_ * D_ / 4) / 256, 256, 0, stream>>>(P2, x, out);
}

// Round 10
// 406.806 us; speedup vs baseline: 1.1388x; 1.0520x over previous
//
#include <hip/hip_runtime.h>
#include <hip/hip_bf16.h>

typedef __hip_bfloat16 bf16;
typedef __bf16 bf16x8 __attribute__((ext_vector_type(8)));
typedef float f32x4 __attribute__((ext_vector_type(4)));

#define B_  2
#define L_  2048
#define D_  1024
#define DIN 2048
#define NST 16
#define T_  (B_ * L_)   // 4096 tokens
#define NCH 32          // scan chunks per sequence
#define CH  64          // tokens per chunk
#define NEXT 2176       // DIN + 128 fused B/C columns for gemm<1>

// Static fallback scratch if harness d_ws is too small (~176 MiB needed).
#define WS_NEEDED 176000000ull
__device__ __align__(256) char g_scratch[184549376];   // 176 MiB

__device__ __forceinline__ float b2f(bf16 v) { return __bfloat162float(v); }
__device__ __forceinline__ bf16 f2b(float v) { return __float2bfloat16(v); }

__device__ __forceinline__ void async16(const bf16* g, bf16* l) {
    __builtin_amdgcn_global_load_lds((const __attribute__((address_space(1))) unsigned int*)g,
                                     (__attribute__((address_space(3))) unsigned int*)l, 16, 0, 0);
}

// ---------------------------------------------------------------- fused prep: 3 transposes + bcw + LN
// flat grid: [0,4096) w_in^T | [4096,8192) w_delta^T | [8192,10240) w_out^T
//            [10240,11264) bcw | [11264,15360) layernorm
__device__ __forceinline__ void tr_tile(const float* __restrict__ in, bf16* __restrict__ out,
                                        int R, int C, int bxx, int byy, float t[32][33]) {
    int c0 = bxx * 32, r0 = byy * 32;
    int tx = threadIdx.x & 31, ty = threadIdx.x >> 5;
    #pragma unroll
    for (int i = 0; i < 32; i += 8)
        t[ty + i][tx] = in[(size_t)(r0 + ty + i) * C + c0 + tx];
    __syncthreads();
    #pragma unroll
    for (int i = 0; i < 32; i += 8)
        out[(size_t)(c0 + ty + i) * R + r0 + tx] = f2b(t[tx][ty + i]);
}

__global__ __launch_bounds__(256) void prep_all(const float* __restrict__ w_in,
                                                const float* __restrict__ w_delta,
                                                const float* __restrict__ w_out,
                                                const float* __restrict__ wb,
                                                const float* __restrict__ wc,
                                                const float* __restrict__ x,
                                                const float* __restrict__ wn,
                                                const float* __restrict__ bn,
                                                bf16* __restrict__ wT_in,
                                                bf16* __restrict__ wT_dbc,
                                                bf16* __restrict__ wT_out,
                                                bf16* __restrict__ xn) {
    __shared__ float t[32][33];
    __shared__ float rs[4], rss[4], mv[2];
    int id = blockIdx.x;
    if (id < 4096) {
        tr_tile(w_in, wT_in, 1024, 4096, id % 128, id / 128, t);
    } else if (id < 8192) {
        int l = id - 4096;
        tr_tile(w_delta, wT_dbc, 2048, 2048, l % 64, l / 64, t);
    } else if (id < 10240) {
        int l = id - 8192;
        tr_tile(w_out, wT_out, 2048, 1024, l % 32, l / 32, t);
    } else if (id < 11264) {
        int l = id - 10240;
        int k = (l % 8) * 256 + threadIdx.x;
        int rn = l / 8;
        float v = 0.f;
        if (rn < 16) v = wb[(size_t)k * 16 + rn];
        else if (rn < 32) v = wc[(size_t)k * 16 + (rn - 16)];
        wT_dbc[(size_t)(2048 + rn) * 2048 + k] = f2b(v);
    } else {
        int tok = id - 11264, tid = threadIdx.x;
        const float* xr = x + (size_t)tok * D_;
        float4 v4 = ((const float4*)xr)[tid];
        float v[4] = {v4.x, v4.y, v4.z, v4.w};
        float s = 0.f, ss = 0.f;
        #pragma unroll
        for (int i = 0; i < 4; i++) { s += v[i]; ss += v[i] * v[i]; }
        #pragma unroll
        for (int o = 32; o > 0; o >>= 1) { s += __shfl_down(s, o); ss += __shfl_down(ss, o); }
        if ((tid & 63) == 0) { rs[tid >> 6] = s; rss[tid >> 6] = ss; }
        __syncthreads();
        if (tid == 0) {
            float S = rs[0] + rs[1] + rs[2] + rs[3];
            float SS = rss[0] + rss[1] + rss[2] + rss[3];
            float mu = S * (1.f / D_);
            float var = SS * (1.f / D_) - mu * mu;
            mv[0] = mu; mv[1] = rsqrtf(fmaxf(var, 0.f) + 1e-5f);
        }
        __syncthreads();
        float mu = mv[0], rstd = mv[1];
        float4 wv = ((const float4*)wn)[tid];
        float4 bv = ((const float4*)bn)[tid];
        float wa[4] = {wv.x, wv.y, wv.z, wv.w};
        float ba[4] = {bv.x, bv.y, bv.z, bv.w};
        union { uint2 u; bf16 h[4]; } q;
        #pragma unroll
        for (int i = 0; i < 4; i++)
            q.h[i] = f2b((v[i] - mu) * rstd * wa[i] + ba[i]);
        ((uint2*)(xn + (size_t)tok * D_))[tid] = q.u;
    }
}

// ---------------------------------------------------------------- GEMM 128x128 (m97), split-K capable
// C[M,N] = A[M,K] @ Bt[N,K]^T over K slice [z*K,(z+1)*K)
// XCD swizzle: id%8 = XCD -> each XCD owns a 4-row-band strip (A L2-resident per XCD).
// EPI 0: store bf16 | 3: store bf16 partial at Cout + z*partStride
template <int EPI>
__global__ __launch_bounds__(256) void gemm128(const bf16* __restrict__ A,
                                               const bf16* __restrict__ Bt,
                                               int K, int lda, int ldb,
                                               void* __restrict__ Cout, int ldc,
                                               size_t partStride) {
    __shared__ __align__(16) bf16 As[128 * 32];
    __shared__ __align__(16) bf16 Bs[128 * 32];
    const int tid = threadIdx.x;
    const int lane = tid & 63;
    const int wave = tid >> 6;
    int id = blockIdx.y * gridDim.x + blockIdx.x;
    int xcd = id & 7;
    int t8 = id >> 3;
    int byi = xcd * 4 + (t8 & 3);
    int bxi = t8 >> 2;
    const int bm = byi * 128, bn = bxi * 128;
    const int wm = (wave & 1) * 64, wn = (wave >> 1) * 64;
    const int kz = blockIdx.z * K;
    f32x4 acc[4][4];
    #pragma unroll
    for (int i = 0; i < 4; i++)
        #pragma unroll
        for (int j = 0; j < 4; j++) acc[i][j] = (f32x4){0.f, 0.f, 0.f, 0.f};

    const int r = tid >> 2;
    const int c = tid & 3;
    const bf16* ga  = A  + (size_t)(bm + r) * lda + kz + c * 8;
    const bf16* gb  = Bt + (size_t)(bn + r) * ldb + kz + c * 8;
    const bf16* ga2 = ga + (size_t)64 * lda;
    const bf16* gb2 = gb + (size_t)64 * ldb;
    bf16* la  = As + tid * 8;           // wave-uniform base + lane*16B
    bf16* lb  = Bs + tid * 8;
    bf16* la2 = la + 64 * 32;
    bf16* lb2 = lb + 64 * 32;

    const int fm = lane & 15;
    const int fk = (lane >> 4) * 8;

    for (int k0 = 0; k0 < K; k0 += 32) {
        async16(ga + k0, la);
        async16(ga2 + k0, la2);
        async16(gb + k0, lb);
        async16(gb2 + k0, lb2);
        __syncthreads();
        bf16x8 af[4], bfr[4];
        #pragma unroll
        for (int i = 0; i < 4; i++)
            af[i] = *(const bf16x8*)(As + (wm + i * 16 + fm) * 32 + fk);
        #pragma unroll
        for (int j = 0; j < 4; j++)
            bfr[j] = *(const bf16x8*)(Bs + (wn + j * 16 + fm) * 32 + fk);
        #pragma unroll
        for (int i = 0; i < 4; i++)
            #pragma unroll
            for (int j = 0; j < 4; j++)
                acc[i][j] = __builtin_amdgcn_mfma_f32_16x16x32_bf16(af[i], bfr[j], acc[i][j], 0, 0, 0);
        __syncthreads();
    }

    const int cn = lane & 15;
    const int r4 = (lane >> 4) * 4;
    bf16* Cp = (bf16*)Cout + (size_t)blockIdx.z * partStride;
    #pragma unroll
    for (int i = 0; i < 4; i++) {
        #pragma unroll
        for (int j = 0; j < 4; j++) {
            int row = bm + wm + i * 16 + r4;
            int col = bn + wn + j * 16 + cn;
            #pragma unroll
            for (int rr = 0; rr < 4; rr++) {
                float v = acc[i][j][rr];
                size_t idx = (size_t)(row + rr) * ldc + col;
                if (EPI == 0) ((bf16*)Cout)[idx] = f2b(v);
                else          Cp[idx] = f2b(v);
            }
        }
    }
}

// ---------------------------------------------------------------- split-K combines (bf16 partials)
// P: 2 bf16 partials of (T_, NEXT). cols<2048: +bias, softplus -> delta(bf16); 2048..2079 -> Bq/Cq
__global__ __launch_bounds__(256) void combine1(const bf16* __restrict__ P,
                                                const float* __restrict__ bias,
                                                bf16* __restrict__ delta,
                                                float* __restrict__ Bq,
                                                float* __restrict__ Cq) {
    const int NF = NEXT / 4;   // 544
    int i = blockIdx.x * 256 + threadIdx.x;
    if (i >= T_ * NF) return;
    int row = i / NF;
    int col = (i - row * NF) * 4;
    union { uint2 u; bf16 h[4]; } a, b;
    a.u = ((const uint2*)P)[i];
    b.u = ((const uint2*)(P + (size_t)T_ * NEXT))[i];
    float v[4];
    #pragma unroll
    for (int j = 0; j < 4; j++) v[j] = b2f(a.h[j]) + b2f(b.h[j]);
    if (col < 2048) {
        const float* bs = bias + col;
        union { uint2 u; bf16 h[4]; } o;
        #pragma unroll
        for (int j = 0; j < 4; j++) {
            float u = v[j] + bs[j];
            o.h[j] = f2b((u > 15.f) ? u : log1pf(__expf(u)));
        }
        *(uint2*)(delta + (size_t)row * 2048 + col) = o.u;
    } else if (col < 2064) {
        *(float4*)(Bq + (size_t)row * 16 + (col - 2048)) = (float4){v[0], v[1], v[2], v[3]};
    } else if (col < 2080) {
        *(float4*)(Cq + (size_t)row * 16 + (col - 2064)) = (float4){v[0], v[1], v[2], v[3]};
    }
}

// P: 4 bf16 partials of (T_, D_). out = sum + residual x (fp32)
__global__ __launch_bounds__(256) void combine2(const bf16* __restrict__ P,
                                                const float* __restrict__ x,
                                                float* __restrict__ out) {
    int i = blockIdx.x * 256 + threadIdx.x;   // over T_*D_/4
    const size_t ps = (size_t)T_ * D_;
    union { uint2 u; bf16 h[4]; } a, b, c, d;
    a.u = ((const uint2*)P)[i];
    b.u = ((const uint2*)(P + ps))[i];
    c.u = ((const uint2*)(P + 2 * ps))[i];
    d.u = ((const uint2*)(P + 3 * ps))[i];
    float4 xr = ((const float4*)x)[i];
    float4 o = {b2f(a.h[0]) + b2f(b.h[0]) + b2f(c.h[0]) + b2f(d.h[0]) + xr.x,
                b2f(a.h[1]) + b2f(b.h[1]) + b2f(c.h[1]) + b2f(d.h[1]) + xr.y,
                b2f(a.h[2]) + b2f(b.h[2]) + b2f(c.h[2]) + b2f(d.h[2]) + xr.z,
                b2f(a.h[3]) + b2f(b.h[3]) + b2f(c.h[3]) + b2f(d.h[3]) + xr.w};
    ((float4*)out)[i] = o;
}

// ---------------------------------------------------------------- depthwise causal conv + SiLU
__global__ __launch_bounds__(256) void conv_kernel(const bf16* __restrict__ xz,
                                                   const float* __restrict__ wconv,
                                                   const float* __restrict__ bconv,
                                                   bf16* __restrict__ xs) {
    int d = blockIdx.x * 256 + threadIdx.x;
    int b = blockIdx.z;
    int l0 = blockIdx.y * 32;
    float w0 = wconv[d * 4 + 0];
    float w1 = wconv[d * 4 + 1];
    float w2 = wconv[d * 4 + 2];
    float w3 = wconv[d * 4 + 3];
    float bc = bconv[d];
    const bf16* base = xz + (size_t)(b * L_) * (2 * DIN) + d;
    float xm3 = (l0 >= 3) ? b2f(base[(size_t)(l0 - 3) * (2 * DIN)]) : 0.f;
    float xm2 = (l0 >= 2) ? b2f(base[(size_t)(l0 - 2) * (2 * DIN)]) : 0.f;
    float xm1 = (l0 >= 1) ? b2f(base[(size_t)(l0 - 1) * (2 * DIN)]) : 0.f;
    for (int l = l0; l < l0 + 32; ++l) {
        float cur = b2f(base[(size_t)l * (2 * DIN)]);
        float v = fmaf(w0, xm3, fmaf(w1, xm2, fmaf(w2, xm1, fmaf(w3, cur, bc))));
        float s = v / (1.f + __expf(-v));
        xs[(size_t)(b * L_ + l) * DIN + d] = f2b(s);
        xm3 = xm2; xm2 = xm1; xm1 = cur;
    }
}

// ---------------------------------------------------------------- chunked selective scan
__global__ __launch_bounds__(256) void scan_passA(const bf16* __restrict__ delta,
                                                  const bf16* __restrict__ xs,
                                                  const float* __restrict__ Bq,
                                                  const float* __restrict__ A_log,
                                                  float* __restrict__ hend,
                                                  float* __restrict__ aprod) {
    __shared__ float Bsh[CH * 16];
    const int d = blockIdx.x * 256 + threadIdx.x;
    const int c = blockIdx.y, b = blockIdx.z;
    const int t0 = b * L_ + c * CH;
    for (int i = threadIdx.x; i < CH * 16; i += 256)
        Bsh[i] = Bq[(size_t)t0 * 16 + i];
    float A[NST], h[NST], ap[NST];
    {
        const float4* al = (const float4*)(A_log + d * 16);
        #pragma unroll
        for (int q = 0; q < 4; q++) {
            float4 v = al[q];
            A[q * 4 + 0] = -__expf(v.x); A[q * 4 + 1] = -__expf(v.y);
            A[q * 4 + 2] = -__expf(v.z); A[q * 4 + 3] = -__expf(v.w);
        }
    }
    #pragma unroll
    for (int n = 0; n < NST; n++) { h[n] = 0.f; ap[n] = 1.f; }
    __syncthreads();
    for (int tt = 0; tt < CH; ++tt) {
        int t = t0 + tt;
        float dlt = b2f(delta[(size_t)t * DIN + d]);
        float dx = dlt * b2f(xs[(size_t)t * DIN + d]);
        #pragma unroll
        for (int n = 0; n < NST; n++) {
            float a = __expf(dlt * A[n]);
            h[n] = fmaf(a, h[n], dx * Bsh[tt * 16 + n]);
            ap[n] *= a;
        }
    }
    size_t base = ((size_t)(b * NCH + c) * DIN + d) * 16;
    #pragma unroll
    for (int q = 0; q < 4; q++) {
        ((float4*)(hend + base))[q]  = (float4){h[q*4], h[q*4+1], h[q*4+2], h[q*4+3]};
        ((float4*)(aprod + base))[q] = (float4){ap[q*4], ap[q*4+1], ap[q*4+2], ap[q*4+3]};
    }
}

__global__ __launch_bounds__(256) void scan_passB(const float* __restrict__ hend,
                                                  const float* __restrict__ aprod,
                                                  float* __restrict__ hinit) {
    int tid = blockIdx.x * 256 + threadIdx.x;
    int b = tid >> 15;
    int dn = tid & 32767;
    float h = 0.f;
    size_t base = (size_t)b * NCH * DIN * 16 + dn;
    for (int c = 0; c < NCH; ++c) {
        size_t idx = base + (size_t)c * DIN * 16;
        hinit[idx] = h;
        h = fmaf(aprod[idx], h, hend[idx]);
    }
}

__global__ __launch_bounds__(256) void scan_passC(const bf16* __restrict__ delta,
                                                  const bf16* __restrict__ xs,
                                                  const float* __restrict__ Bq,
                                                  const float* __restrict__ Cq,
                                                  const float* __restrict__ A_log,
                                                  const float* __restrict__ Dp,
                                                  const bf16* __restrict__ xz,
                                                  const float* __restrict__ hinit,
                                                  bf16* __restrict__ gbuf) {
    __shared__ float Bsh[CH * 16];
    __shared__ float Csh[CH * 16];
    const int d = blockIdx.x * 256 + threadIdx.x;
    const int c = blockIdx.y, b = blockIdx.z;
    const int t0 = b * L_ + c * CH;
    for (int i = threadIdx.x; i < CH * 16; i += 256) {
        Bsh[i] = Bq[(size_t)t0 * 16 + i];
        Csh[i] = Cq[(size_t)t0 * 16 + i];
    }
    float A[NST], h[NST];
    {
        const float4* al = (const float4*)(A_log + d * 16);
        #pragma unroll
        for (int q = 0; q < 4; q++) {
            float4 v = al[q];
            A[q * 4 + 0] = -__expf(v.x); A[q * 4 + 1] = -__expf(v.y);
            A[q * 4 + 2] = -__expf(v.z); A[q * 4 + 3] = -__expf(v.w);
        }
    }
    {
        size_t base = ((size_t)(b * NCH + c) * DIN + d) * 16;
        #pragma unroll
        for (int q = 0; q < 4; q++) {
            float4 v = ((const float4*)(hinit + base))[q];
            h[q * 4 + 0] = v.x; h[q * 4 + 1] = v.y; h[q * 4 + 2] = v.z; h[q * 4 + 3] = v.w;
        }
    }
    float Dd = Dp[d];
    __syncthreads();
    for (int tt = 0; tt < CH; ++tt) {
        int t = t0 + tt;
        float dlt = b2f(delta[(size_t)t * DIN + d]);
        float xv = b2f(xs[(size_t)t * DIN + d]);
        float dx = dlt * xv;
        float y = Dd * xv;
        #pragma unroll
        for (int n = 0; n < NST; n++) {
            float a = __expf(dlt * A[n]);
            h[n] = fmaf(a, h[n], dx * Bsh[tt * 16 + n]);
            y = fmaf(h[n], Csh[tt * 16 + n], y);
        }
        float zv = b2f(xz[(size_t)t * (2 * DIN) + DIN + d]);
        float gg = y * (zv / (1.f + __expf(-zv)));
        gbuf[(size_t)t * DIN + d] = f2b(gg);
    }
}

// ---------------------------------------------------------------- launch
extern "C" void kernel_launch(void* const* d_in, const int* in_sizes, int n_in,
                              void* d_out, int out_size, void* d_ws, size_t ws_size,
                              hipStream_t stream) {
    const float* x       = (const float*)d_in[0];
    const float* w_norm  = (const float*)d_in[1];
    const float* b_norm  = (const float*)d_in[2];
    const float* w_in    = (const float*)d_in[3];
    const float* w_conv  = (const float*)d_in[4];
    const float* b_conv  = (const float*)d_in[5];
    const float* A_log   = (const float*)d_in[6];
    const float* w_b     = (const float*)d_in[7];
    const float* w_c     = (const float*)d_in[8];
    const float* w_delta = (const float*)d_in[9];
    const float* b_delta = (const float*)d_in[10];
    const float* D_param = (const float*)d_in[11];
    const float* w_out   = (const float*)d_in[12];
    float* out = (float*)d_out;

    char* p = (char*)d_ws;
    if (ws_size < WS_NEEDED) {
        void* sp = nullptr;
        hipGetSymbolAddress(&sp, HIP_SYMBOL(g_scratch));
        p = (char*)sp;
    }
    auto alloc = [&](size_t bytes) { char* q = p; p += (bytes + 255) & ~255ull; return q; };

    bf16* wT_in    = (bf16*)alloc((size_t)4096 * 1024 * 2);
    bf16* wT_dbc   = (bf16*)alloc((size_t)NEXT * 2048 * 2);
    bf16* wT_out   = (bf16*)alloc((size_t)1024 * 2048 * 2);
    bf16* xn       = (bf16*)alloc((size_t)T_ * D_ * 2);
    bf16* xz       = (bf16*)alloc((size_t)T_ * 2 * DIN * 2);
    bf16* xs       = (bf16*)alloc((size_t)T_ * DIN * 2);
    bf16* delta    = (bf16*)alloc((size_t)T_ * DIN * 2);
    float* Bq      = (float*)alloc((size_t)T_ * NST * 4);
    float* Cq      = (float*)alloc((size_t)T_ * NST * 4);
    bf16* gbuf     = (bf16*)alloc((size_t)T_ * DIN * 2);
    float* hend    = (float*)alloc((size_t)B_ * NCH * DIN * NST * 4);
    float* aprod   = (float*)alloc((size_t)B_ * NCH * DIN * NST * 4);
    float* hinit   = (float*)alloc((size_t)B_ * NCH * DIN * NST * 4);
    bf16* P1       = (bf16*)alloc((size_t)2 * T_ * NEXT * 2);   // aliased as P2 (4 x T_ x D_ bf16)
    bf16* P2       = P1;   // 33.6 MB <= 35.7 MB; P1 dead after combine1

    // fused prep: transposes + bcw + layernorm, one dispatch
    prep_all<<<15360, 256, 0, stream>>>(w_in, w_delta, w_out, w_b, w_c, x, w_norm, b_norm,
                                        wT_in, wT_dbc, wT_out, xn);

    // xz = xn @ w_in  (M=4096, N=4096, K=1024), 1024 blocks
    gemm128<0><<<dim3(32, 32, 1), 256, 0, stream>>>(xn, wT_in, 1024, 1024, 1024,
                                                    xz, 4096, 0);

    conv_kernel<<<dim3(DIN / 256, L_ / 32, B_), 256, 0, stream>>>(xz, w_conv, b_conv, xs);

    // P1[z] = xs @ [w_delta|w_b|w_c] K-slice  (M=4096, N=2176, split-K=2), 1088 blocks
    gemm128<3><<<dim3(NEXT / 128, 32, 2), 256, 0, stream>>>(xs, wT_dbc, 1024, 2048, 2048,
                                                            P1, NEXT, (size_t)T_ * NEXT);
    combine1<<<(T_ * (NEXT / 4) + 255) / 256, 256, 0, stream>>>(P1, b_delta, delta, Bq, Cq);

    scan_passA<<<dim3(DIN / 256, NCH, B_), 256, 0, stream>>>(delta, xs, Bq, A_log, hend, aprod);
    scan_passB<<<(B_ * DIN * NST) / 256, 256, 0, stream>>>(hend, aprod, hinit);
    scan_passC<<<dim3(DIN / 256, NCH, B_), 256, 0, stream>>>(delta, xs, Bq, Cq, A_log, D_param,
                                                             xz, hinit, gbuf);

    // P2[z] = gbuf @ w_out K-slice  (M=4096, N=1024, split-K=4), 1024 blocks
    gemm128<3><<<dim3(8, 32, 4), 256, 0, stream>>>(gbuf, wT_out, 512, 2048, 2048,
                                                   P2, 1024, (size_t)T_ * D_);
    combine2<<<(T_ * D_ / 4) / 256, 256, 0, stream>>>(P2, x, out);
}

// Round 11
// 392.941 us; speedup vs baseline: 1.1790x; 1.0353x over previous
//
#include <hip/hip_runtime.h>
#include <hip/hip_bf16.h>

typedef __hip_bfloat16 bf16;
typedef __bf16 bf16x8 __attribute__((ext_vector_type(8)));
typedef float f32x4 __attribute__((ext_vector_type(4)));

#define B_  2
#define L_  2048
#define D_  1024
#define DIN 2048
#define NST 16
#define T_  (B_ * L_)   // 4096 tokens
#define NCH 32          // scan chunks per sequence
#define CH  64          // tokens per chunk
#define NEXT 2176       // DIN + 128 fused B/C columns for gemm<1>

// Static fallback scratch if harness d_ws is too small (~176 MiB needed).
#define WS_NEEDED 176000000ull
__device__ __align__(256) char g_scratch[184549376];   // 176 MiB

__device__ __forceinline__ float b2f(bf16 v) { return __bfloat162float(v); }
__device__ __forceinline__ bf16 f2b(float v) { return __float2bfloat16(v); }

__device__ __forceinline__ void async16(const bf16* g, bf16* l) {
    __builtin_amdgcn_global_load_lds((const __attribute__((address_space(1))) unsigned int*)g,
                                     (__attribute__((address_space(3))) unsigned int*)l, 16, 0, 0);
}

// ---------------------------------------------------------------- fused prep: 3 transposes + bcw + LN
__device__ __forceinline__ void tr_tile(const float* __restrict__ in, bf16* __restrict__ out,
                                        int R, int C, int bxx, int byy, float t[32][33]) {
    int c0 = bxx * 32, r0 = byy * 32;
    int tx = threadIdx.x & 31, ty = threadIdx.x >> 5;
    #pragma unroll
    for (int i = 0; i < 32; i += 8)
        t[ty + i][tx] = in[(size_t)(r0 + ty + i) * C + c0 + tx];
    __syncthreads();
    #pragma unroll
    for (int i = 0; i < 32; i += 8)
        out[(size_t)(c0 + ty + i) * R + r0 + tx] = f2b(t[tx][ty + i]);
}

__global__ __launch_bounds__(256) void prep_all(const float* __restrict__ w_in,
                                                const float* __restrict__ w_delta,
                                                const float* __restrict__ w_out,
                                                const float* __restrict__ wb,
                                                const float* __restrict__ wc,
                                                const float* __restrict__ x,
                                                const float* __restrict__ wn,
                                                const float* __restrict__ bn,
                                                bf16* __restrict__ wT_in,
                                                bf16* __restrict__ wT_dbc,
                                                bf16* __restrict__ wT_out,
                                                bf16* __restrict__ xn) {
    __shared__ float t[32][33];
    __shared__ float rs[4], rss[4], mv[2];
    int id = blockIdx.x;
    if (id < 4096) {
        tr_tile(w_in, wT_in, 1024, 4096, id % 128, id / 128, t);
    } else if (id < 8192) {
        int l = id - 4096;
        tr_tile(w_delta, wT_dbc, 2048, 2048, l % 64, l / 64, t);
    } else if (id < 10240) {
        int l = id - 8192;
        tr_tile(w_out, wT_out, 2048, 1024, l % 32, l / 32, t);
    } else if (id < 11264) {
        int l = id - 10240;
        int k = (l % 8) * 256 + threadIdx.x;
        int rn = l / 8;
        float v = 0.f;
        if (rn < 16) v = wb[(size_t)k * 16 + rn];
        else if (rn < 32) v = wc[(size_t)k * 16 + (rn - 16)];
        wT_dbc[(size_t)(2048 + rn) * 2048 + k] = f2b(v);
    } else {
        int tok = id - 11264, tid = threadIdx.x;
        const float* xr = x + (size_t)tok * D_;
        float4 v4 = ((const float4*)xr)[tid];
        float v[4] = {v4.x, v4.y, v4.z, v4.w};
        float s = 0.f, ss = 0.f;
        #pragma unroll
        for (int i = 0; i < 4; i++) { s += v[i]; ss += v[i] * v[i]; }
        #pragma unroll
        for (int o = 32; o > 0; o >>= 1) { s += __shfl_down(s, o); ss += __shfl_down(ss, o); }
        if ((tid & 63) == 0) { rs[tid >> 6] = s; rss[tid >> 6] = ss; }
        __syncthreads();
        if (tid == 0) {
            float S = rs[0] + rs[1] + rs[2] + rs[3];
            float SS = rss[0] + rss[1] + rss[2] + rss[3];
            float mu = S * (1.f / D_);
            float var = SS * (1.f / D_) - mu * mu;
            mv[0] = mu; mv[1] = rsqrtf(fmaxf(var, 0.f) + 1e-5f);
        }
        __syncthreads();
        float mu = mv[0], rstd = mv[1];
        float4 wv = ((const float4*)wn)[tid];
        float4 bv = ((const float4*)bn)[tid];
        float wa[4] = {wv.x, wv.y, wv.z, wv.w};
        float ba[4] = {bv.x, bv.y, bv.z, bv.w};
        union { uint2 u; bf16 h[4]; } q;
        #pragma unroll
        for (int i = 0; i < 4; i++)
            q.h[i] = f2b((v[i] - mu) * rstd * wa[i] + ba[i]);
        ((uint2*)(xn + (size_t)tok * D_))[tid] = q.u;
    }
}

// ---------------------------------------------------------------- GEMM 128x128, BK=64, XOR-swizzled LDS
// C[M,N] = A[M,K] @ Bt[N,K]^T over K slice [z*K,(z+1)*K). K % 64 == 0.
// LDS layout [128][64]: slot s of row r holds k-chunk (s ^ (r&7)) -> fragment reads
// hit 8 bank-groups at 2-way aliasing (free, m136) while async16 dest stays flat lane*16B.
// XCD swizzle: id%8 = XCD -> 4-row-band strips (A L2-resident per XCD).
// EPI 0: store bf16 | 3: store bf16 partial at Cout + z*partStride
template <int EPI>
__global__ __launch_bounds__(256) void gemm128(const bf16* __restrict__ A,
                                               const bf16* __restrict__ Bt,
                                               int K, int lda, int ldb,
                                               void* __restrict__ Cout, int ldc,
                                               size_t partStride) {
    __shared__ __align__(16) bf16 As[128 * 64];
    __shared__ __align__(16) bf16 Bs[128 * 64];
    const int tid = threadIdx.x;
    const int lane = tid & 63;
    const int wave = tid >> 6;
    int id = blockIdx.y * gridDim.x + blockIdx.x;
    int xcd = id & 7;
    int t8 = id >> 3;
    int byi = xcd * 4 + (t8 & 3);
    int bxi = t8 >> 2;
    const int bm = byi * 128, bn = bxi * 128;
    const int wm = (wave & 1) * 64, wn = (wave >> 1) * 64;
    const int kz = blockIdx.z * K;
    f32x4 acc[4][4];
    #pragma unroll
    for (int i = 0; i < 4; i++)
        #pragma unroll
        for (int j = 0; j < 4; j++) acc[i][j] = (f32x4){0.f, 0.f, 0.f, 0.f};

    // staging: instruction i covers flat chunks j = i*256+tid; row=j>>3, slot=j&7,
    // global chunk = slot ^ (row&7)
    const bf16* gA[4];
    const bf16* gB[4];
    bf16* lA[4];
    bf16* lB[4];
    #pragma unroll
    for (int i = 0; i < 4; i++) {
        int j = i * 256 + tid;
        int row = j >> 3;
        int cg = (j & 7) ^ (row & 7);
        gA[i] = A  + (size_t)(bm + row) * lda + kz + cg * 8;
        gB[i] = Bt + (size_t)(bn + row) * ldb + kz + cg * 8;
        lA[i] = As + j * 8;
        lB[i] = Bs + j * 8;
    }

    const int fm = lane & 15;
    const int fk = (lane >> 4) * 8;

    for (int k0 = 0; k0 < K; k0 += 64) {
        #pragma unroll
        for (int i = 0; i < 4; i++) async16(gA[i] + k0, lA[i]);
        #pragma unroll
        for (int i = 0; i < 4; i++) async16(gB[i] + k0, lB[i]);
        __syncthreads();
        #pragma unroll
        for (int kk = 0; kk < 64; kk += 32) {
            bf16x8 af[4], bfr[4];
            #pragma unroll
            for (int i = 0; i < 4; i++) {
                int R = wm + i * 16 + fm;
                af[i] = *(const bf16x8*)(As + R * 64 + ((((kk + fk) >> 3) ^ (R & 7)) * 8));
            }
            #pragma unroll
            for (int j = 0; j < 4; j++) {
                int R = wn + j * 16 + fm;
                bfr[j] = *(const bf16x8*)(Bs + R * 64 + ((((kk + fk) >> 3) ^ (R & 7)) * 8));
            }
            #pragma unroll
            for (int i = 0; i < 4; i++)
                #pragma unroll
                for (int j = 0; j < 4; j++)
                    acc[i][j] = __builtin_amdgcn_mfma_f32_16x16x32_bf16(af[i], bfr[j], acc[i][j], 0, 0, 0);
        }
        __syncthreads();
    }

    const int cn = lane & 15;
    const int r4 = (lane >> 4) * 4;
    bf16* Cp = (bf16*)Cout + (size_t)blockIdx.z * partStride;
    #pragma unroll
    for (int i = 0; i < 4; i++) {
        #pragma unroll
        for (int j = 0; j < 4; j++) {
            int row = bm + wm + i * 16 + r4;
            int col = bn + wn + j * 16 + cn;
            #pragma unroll
            for (int rr = 0; rr < 4; rr++) {
                float v = acc[i][j][rr];
                size_t idx = (size_t)(row + rr) * ldc + col;
                if (EPI == 0) ((bf16*)Cout)[idx] = f2b(v);
                else          Cp[idx] = f2b(v);
            }
        }
    }
}

// ---------------------------------------------------------------- split-K combines (bf16 partials)
__global__ __launch_bounds__(256) void combine1(const bf16* __restrict__ P,
                                                const float* __restrict__ bias,
                                                bf16* __restrict__ delta,
                                                float* __restrict__ Bq,
                                                float* __restrict__ Cq) {
    const int NF = NEXT / 4;   // 544
    int i = blockIdx.x * 256 + threadIdx.x;
    if (i >= T_ * NF) return;
    int row = i / NF;
    int col = (i - row * NF) * 4;
    union { uint2 u; bf16 h[4]; } a, b;
    a.u = ((const uint2*)P)[i];
    b.u = ((const uint2*)(P + (size_t)T_ * NEXT))[i];
    float v[4];
    #pragma unroll
    for (int j = 0; j < 4; j++) v[j] = b2f(a.h[j]) + b2f(b.h[j]);
    if (col < 2048) {
        const float* bs = bias + col;
        union { uint2 u; bf16 h[4]; } o;
        #pragma unroll
        for (int j = 0; j < 4; j++) {
            float u = v[j] + bs[j];
            o.h[j] = f2b((u > 15.f) ? u : log1pf(__expf(u)));
        }
        *(uint2*)(delta + (size_t)row * 2048 + col) = o.u;
    } else if (col < 2064) {
        *(float4*)(Bq + (size_t)row * 16 + (col - 2048)) = (float4){v[0], v[1], v[2], v[3]};
    } else if (col < 2080) {
        *(float4*)(Cq + (size_t)row * 16 + (col - 2064)) = (float4){v[0], v[1], v[2], v[3]};
    }
}

__global__ __launch_bounds__(256) void combine2(const bf16* __restrict__ P,
                                                const float* __restrict__ x,
                                                float* __restrict__ out) {
    int i = blockIdx.x * 256 + threadIdx.x;   // over T_*D_/4
    const size_t ps = (size_t)T_ * D_;
    union { uint2 u; bf16 h[4]; } a, b, c, d;
    a.u = ((const uint2*)P)[i];
    b.u = ((const uint2*)(P + ps))[i];
    c.u = ((const uint2*)(P + 2 * ps))[i];
    d.u = ((const uint2*)(P + 3 * ps))[i];
    float4 xr = ((const float4*)x)[i];
    float4 o = {b2f(a.h[0]) + b2f(b.h[0]) + b2f(c.h[0]) + b2f(d.h[0]) + xr.x,
                b2f(a.h[1]) + b2f(b.h[1]) + b2f(c.h[1]) + b2f(d.h[1]) + xr.y,
                b2f(a.h[2]) + b2f(b.h[2]) + b2f(c.h[2]) + b2f(d.h[2]) + xr.z,
                b2f(a.h[3]) + b2f(b.h[3]) + b2f(c.h[3]) + b2f(d.h[3]) + xr.w};
    ((float4*)out)[i] = o;
}

// ---------------------------------------------------------------- depthwise causal conv + SiLU
__global__ __launch_bounds__(256) void conv_kernel(const bf16* __restrict__ xz,
                                                   const float* __restrict__ wconv,
                                                   const float* __restrict__ bconv,
                                                   bf16* __restrict__ xs) {
    int d = blockIdx.x * 256 + threadIdx.x;
    int b = blockIdx.z;
    int l0 = blockIdx.y * 32;
    float w0 = wconv[d * 4 + 0];
    float w1 = wconv[d * 4 + 1];
    float w2 = wconv[d * 4 + 2];
    float w3 = wconv[d * 4 + 3];
    float bc = bconv[d];
    const bf16* base = xz + (size_t)(b * L_) * (2 * DIN) + d;
    float xm3 = (l0 >= 3) ? b2f(base[(size_t)(l0 - 3) * (2 * DIN)]) : 0.f;
    float xm2 = (l0 >= 2) ? b2f(base[(size_t)(l0 - 2) * (2 * DIN)]) : 0.f;
    float xm1 = (l0 >= 1) ? b2f(base[(size_t)(l0 - 1) * (2 * DIN)]) : 0.f;
    for (int l = l0; l < l0 + 32; ++l) {
        float cur = b2f(base[(size_t)l * (2 * DIN)]);
        float v = fmaf(w0, xm3, fmaf(w1, xm2, fmaf(w2, xm1, fmaf(w3, cur, bc))));
        float s = v / (1.f + __expf(-v));
        xs[(size_t)(b * L_ + l) * DIN + d] = f2b(s);
        xm3 = xm2; xm2 = xm1; xm1 = cur;
    }
}

// ---------------------------------------------------------------- chunked selective scan
__global__ __launch_bounds__(256) void scan_passA(const bf16* __restrict__ delta,
                                                  const bf16* __restrict__ xs,
                                                  const float* __restrict__ Bq,
                                                  const float* __restrict__ A_log,
                                                  float* __restrict__ hend,
                                                  float* __restrict__ aprod) {
    __shared__ float Bsh[CH * 16];
    const int d = blockIdx.x * 256 + threadIdx.x;
    const int c = blockIdx.y, b = blockIdx.z;
    const int t0 = b * L_ + c * CH;
    for (int i = threadIdx.x; i < CH * 16; i += 256)
        Bsh[i] = Bq[(size_t)t0 * 16 + i];
    float A[NST], h[NST], ap[NST];
    {
        const float4* al = (const float4*)(A_log + d * 16);
        #pragma unroll
        for (int q = 0; q < 4; q++) {
            float4 v = al[q];
            A[q * 4 + 0] = -__expf(v.x); A[q * 4 + 1] = -__expf(v.y);
            A[q * 4 + 2] = -__expf(v.z); A[q * 4 + 3] = -__expf(v.w);
        }
    }
    #pragma unroll
    for (int n = 0; n < NST; n++) { h[n] = 0.f; ap[n] = 1.f; }
    __syncthreads();
    for (int tt = 0; tt < CH; ++tt) {
        int t = t0 + tt;
        float dlt = b2f(delta[(size_t)t * DIN + d]);
        float dx = dlt * b2f(xs[(size_t)t * DIN + d]);
        #pragma unroll
        for (int n = 0; n < NST; n++) {
            float a = __expf(dlt * A[n]);
            h[n] = fmaf(a, h[n], dx * Bsh[tt * 16 + n]);
            ap[n] *= a;
        }
    }
    size_t base = ((size_t)(b * NCH + c) * DIN + d) * 16;
    #pragma unroll
    for (int q = 0; q < 4; q++) {
        ((float4*)(hend + base))[q]  = (float4){h[q*4], h[q*4+1], h[q*4+2], h[q*4+3]};
        ((float4*)(aprod + base))[q] = (float4){ap[q*4], ap[q*4+1], ap[q*4+2], ap[q*4+3]};
    }
}

__global__ __launch_bounds__(256) void scan_passB(const float* __restrict__ hend,
                                                  const float* __restrict__ aprod,
                                                  float* __restrict__ hinit) {
    int tid = blockIdx.x * 256 + threadIdx.x;
    int b = tid >> 15;
    int dn = tid & 32767;
    float h = 0.f;
    size_t base = (size_t)b * NCH * DIN * 16 + dn;
    for (int c = 0; c < NCH; ++c) {
        size_t idx = base + (size_t)c * DIN * 16;
        hinit[idx] = h;
        h = fmaf(aprod[idx], h, hend[idx]);
    }
}

__global__ __launch_bounds__(256) void scan_passC(const bf16* __restrict__ delta,
                                                  const bf16* __restrict__ xs,
                                                  const float* __restrict__ Bq,
                                                  const float* __restrict__ Cq,
                                                  const float* __restrict__ A_log,
                                                  const float* __restrict__ Dp,
                                                  const bf16* __restrict__ xz,
                                                  const float* __restrict__ hinit,
                                                  bf16* __restrict__ gbuf) {
    __shared__ float Bsh[CH * 16];
    __shared__ float Csh[CH * 16];
    const int d = blockIdx.x * 256 + threadIdx.x;
    const int c = blockIdx.y, b = blockIdx.z;
    const int t0 = b * L_ + c * CH;
    for (int i = threadIdx.x; i < CH * 16; i += 256) {
        Bsh[i] = Bq[(size_t)t0 * 16 + i];
        Csh[i] = Cq[(size_t)t0 * 16 + i];
    }
    float A[NST], h[NST];
    {
        const float4* al = (const float4*)(A_log + d * 16);
        #pragma unroll
        for (int q = 0; q < 4; q++) {
            float4 v = al[q];
            A[q * 4 + 0] = -__expf(v.x); A[q * 4 + 1] = -__expf(v.y);
            A[q * 4 + 2] = -__expf(v.z); A[q * 4 + 3] = -__expf(v.w);
        }
    }
    {
        size_t base = ((size_t)(b * NCH + c) * DIN + d) * 16;
        #pragma unroll
        for (int q = 0; q < 4; q++) {
            float4 v = ((const float4*)(hinit + base))[q];
            h[q * 4 + 0] = v.x; h[q * 4 + 1] = v.y; h[q * 4 + 2] = v.z; h[q * 4 + 3] = v.w;
        }
    }
    float Dd = Dp[d];
    __syncthreads();
    for (int tt = 0; tt < CH; ++tt) {
        int t = t0 + tt;
        float dlt = b2f(delta[(size_t)t * DIN + d]);
        float xv = b2f(xs[(size_t)t * DIN + d]);
        float dx = dlt * xv;
        float y = Dd * xv;
        #pragma unroll
        for (int n = 0; n < NST; n++) {
            float a = __expf(dlt * A[n]);
            h[n] = fmaf(a, h[n], dx * Bsh[tt * 16 + n]);
            y = fmaf(h[n], Csh[tt * 16 + n], y);
        }
        float zv = b2f(xz[(size_t)t * (2 * DIN) + DIN + d]);
        float gg = y * (zv / (1.f + __expf(-zv)));
        gbuf[(size_t)t * DIN + d] = f2b(gg);
    }
}

// ---------------------------------------------------------------- launch
extern "C" void kernel_launch(void* const* d_in, const int* in_sizes, int n_in,
                              void* d_out, int out_size, void* d_ws, size_t ws_size,
                              hipStream_t stream) {
    const float* x       = (const float*)d_in[0];
    const float* w_norm  = (const float*)d_in[1];
    const float* b_norm  = (const float*)d_in[2];
    const float* w_in    = (const float*)d_in[3];
    const float* w_conv  = (const float*)d_in[4];
    const float* b_conv  = (const float*)d_in[5];
    const float* A_log   = (const float*)d_in[6];
    const float* w_b     = (const float*)d_in[7];
    const float* w_c     = (const float*)d_in[8];
    const float* w_delta = (const float*)d_in[9];
    const float* b_delta = (const float*)d_in[10];
    const float* D_param = (const float*)d_in[11];
    const float* w_out   = (const float*)d_in[12];
    float* out = (float*)d_out;

    char* p = (char*)d_ws;
    if (ws_size < WS_NEEDED) {
        void* sp = nullptr;
        hipGetSymbolAddress(&sp, HIP_SYMBOL(g_scratch));
        p = (char*)sp;
    }
    auto alloc = [&](size_t bytes) { char* q = p; p += (bytes + 255) & ~255ull; return q; };

    bf16* wT_in    = (bf16*)alloc((size_t)4096 * 1024 * 2);
    bf16* wT_dbc   = (bf16*)alloc((size_t)NEXT * 2048 * 2);
    bf16* wT_out   = (bf16*)alloc((size_t)1024 * 2048 * 2);
    bf16* xn       = (bf16*)alloc((size_t)T_ * D_ * 2);
    bf16* xz       = (bf16*)alloc((size_t)T_ * 2 * DIN * 2);
    bf16* xs       = (bf16*)alloc((size_t)T_ * DIN * 2);
    bf16* delta    = (bf16*)alloc((size_t)T_ * DIN * 2);
    float* Bq      = (float*)alloc((size_t)T_ * NST * 4);
    float* Cq      = (float*)alloc((size_t)T_ * NST * 4);
    bf16* gbuf     = (bf16*)alloc((size_t)T_ * DIN * 2);
    float* hend    = (float*)alloc((size_t)B_ * NCH * DIN * NST * 4);
    float* aprod   = (float*)alloc((size_t)B_ * NCH * DIN * NST * 4);
    float* hinit   = (float*)alloc((size_t)B_ * NCH * DIN * NST * 4);
    bf16* P1       = (bf16*)alloc((size_t)2 * T_ * NEXT * 2);   // aliased as P2 (4 x T_ x D_ bf16)
    bf16* P2       = P1;

    prep_all<<<15360, 256, 0, stream>>>(w_in, w_delta, w_out, w_b, w_c, x, w_norm, b_norm,
                                        wT_in, wT_dbc, wT_out, xn);

    // xz = xn @ w_in  (M=4096, N=4096, K=1024), 1024 blocks
    gemm128<0><<<dim3(32, 32, 1), 256, 0, stream>>>(xn, wT_in, 1024, 1024, 1024,
                                                    xz, 4096, 0);

    conv_kernel<<<dim3(DIN / 256, L_ / 32, B_), 256, 0, stream>>>(xz, w_conv, b_conv, xs);

    // P1[z] = xs @ [w_delta|w_b|w_c] K-slice  (M=4096, N=2176, split-K=2), 1088 blocks
    gemm128<3><<<dim3(NEXT / 128, 32, 2), 256, 0, stream>>>(xs, wT_dbc, 1024, 2048, 2048,
                                                            P1, NEXT, (size_t)T_ * NEXT);
    combine1<<<(T_ * (NEXT / 4) + 255) / 256, 256, 0, stream>>>(P1, b_delta, delta, Bq, Cq);

    scan_passA<<<dim3(DIN / 256, NCH, B_), 256, 0, stream>>>(delta, xs, Bq, A_log, hend, aprod);
    scan_passB<<<(B_ * DIN * NST) / 256, 256, 0, stream>>>(hend, aprod, hinit);
    scan_passC<<<dim3(DIN / 256, NCH, B_), 256, 0, stream>>>(delta, xs, Bq, Cq, A_log, D_param,
                                                             xz, hinit, gbuf);

    // P2[z] = gbuf @ w_out K-slice  (M=4096, N=1024, split-K=4), 1024 blocks
    gemm128<3><<<dim3(8, 32, 4), 256, 0, stream>>>(gbuf, wT_out, 512, 2048, 2048,
                                                   P2, 1024, (size_t)T_ * D_);
    combine2<<<(T_ * D_ / 4) / 256, 256, 0, stream>>>(P2, x, out);
}